// Round 7
// baseline (1106.577 us; speedup 1.0000x reference)
//
#include <hip/hip_runtime.h>
#include <hip/hip_bf16.h>

#define NN      100000
#define EE      400000
#define QQ      4096
#define CLASSES 10
#define BN_EPS  1e-5f
#define NCHUNK  256

typedef __hip_bfloat16 bf16;
typedef __attribute__((ext_vector_type(8))) short short8v;
typedef __attribute__((ext_vector_type(4))) float float4v;

__device__ inline float ldv(const float* p, long i) { return p[i]; }
__device__ inline float ldv(const bf16*  p, long i) { return __bfloat162float(p[i]); }
__device__ inline void  stv(float* p, long i, float v) { p[i] = v; }
__device__ inline void  stv(bf16*  p, long i, float v) { p[i] = __float2bfloat16(v); }

__device__ inline unsigned short f2b(float f) { bf16 b = __float2bfloat16(f); unsigned short s; __builtin_memcpy(&s, &b, 2); return s; }
__device__ inline float b2f(unsigned short s) { bf16 b; __builtin_memcpy(&b, &s, 2); return __bfloat162float(b); }

__device__ __forceinline__ void gload_lds16(const void* g, void* l) {
    __builtin_amdgcn_global_load_lds(
        (const __attribute__((address_space(1))) void*)g,
        (__attribute__((address_space(3))) void*)l,
        16, 0, 0);
}

// ---------------- zeroing ----------------
__global__ void zero_kernel(float* __restrict__ p, size_t n) {
    size_t i  = (size_t)blockIdx.x * blockDim.x + threadIdx.x;
    size_t st = (size_t)gridDim.x * blockDim.x;
    for (; i < n; i += st) p[i] = 0.f;
}

// ---------------- CSR build ----------------
__global__ void csr_count_kernel(const int* __restrict__ u, const int* __restrict__ v, int E, int* __restrict__ deg) {
    int e = blockIdx.x * 256 + threadIdx.x;
    if (e < E) { atomicAdd(&deg[u[e]], 1); atomicAdd(&deg[v[e]], 1); }
}

__global__ __launch_bounds__(256) void csr_chunksum_kernel(const int* __restrict__ deg, int N, int chunk, int* __restrict__ bsum) {
    __shared__ int sh[256];
    int b = blockIdx.x, tid = threadIdx.x;
    int i0 = b * chunk, i1 = min(N, i0 + chunk);
    int s = 0;
    for (int i = i0 + tid; i < i1; i += 256) s += deg[i];
    sh[tid] = s; __syncthreads();
    for (int st = 128; st > 0; st >>= 1) { if (tid < st) sh[tid] += sh[tid + st]; __syncthreads(); }
    if (tid == 0) bsum[b] = sh[0];
}

__global__ void csr_scanb_kernel(const int* __restrict__ bsum, int* __restrict__ boff) {
    if (threadIdx.x == 0 && blockIdx.x == 0) {
        int r = 0;
        for (int i = 0; i < NCHUNK; ++i) { boff[i] = r; r += bsum[i]; }
    }
}

__global__ void csr_rowp_kernel(const int* __restrict__ deg, const int* __restrict__ boff,
                                int N, int chunk, int* __restrict__ rowp, int* __restrict__ cur) {
    int b = blockIdx.x;
    if (threadIdx.x != 0) return;
    int i0 = b * chunk, i1 = min(N, i0 + chunk);
    int r = boff[b];
    for (int i = i0; i < i1; ++i) { rowp[i] = r; cur[i] = r; r += deg[i]; }
    if (b == NCHUNK - 1) rowp[N] = r;
}

__global__ void csr_fill_kernel(const int* __restrict__ u, const int* __restrict__ v,
                                const float* __restrict__ t, int E,
                                int* __restrict__ cur, int* __restrict__ adj, float* __restrict__ gsum) {
    int e = blockIdx.x * 256 + threadIdx.x;
    if (e >= E) return;
    int a = u[e], b = v[e];
    float tlast = t[E - 1], tfirst = t[0];
    float ge = (tlast - t[e]) / (1.0f + tlast - tfirst);
    int p = atomicAdd(&cur[a], 1); adj[p] = b;
    int q = atomicAdd(&cur[b], 1); adj[q] = a;
    atomicAdd(&gsum[a], ge); atomicAdd(&gsum[b], ge);
}

// ---------------- gather L1 (bf16 input): out[n][0:128]=sum h0b[other], [128]=gsum, [129:136]=0 ----------------
__global__ __launch_bounds__(256) void gather_l1_kernel(
    const bf16* __restrict__ h0b, const int* __restrict__ rowp, const int* __restrict__ adj,
    const float* __restrict__ gsum, bf16* __restrict__ out, int N)
{
    int n = blockIdx.x * 4 + (threadIdx.x >> 6);
    if (n >= N) return;
    int lane = threadIdx.x & 63;
    float a0 = 0.f, a1 = 0.f;
    int j0 = rowp[n], j1 = rowp[n + 1];
    for (int j = j0; j < j1; ++j) {
        int o = adj[j];
        ushort2 x = ((const ushort2*)(h0b + (long)o * 128))[lane];
        a0 += b2f(x.x); a1 += b2f(x.y);
    }
    bf16* orow = out + (long)n * 136;
    ushort2 pv; pv.x = f2b(a0); pv.y = f2b(a1);
    ((ushort2*)orow)[lane] = pv;
    if (lane == 0) {
        orow[128] = __float2bfloat16(gsum[n]);
        orow[129] = __float2bfloat16(0.f);
    } else if (lane < 4) {
        ushort2 z; z.x = 0; z.y = 0;
        ((ushort2*)(orow + 130))[lane - 1] = z;   // cols 130..135
    }
}

// ---------------- gather L2: h1 bf16 ld264 (257 real cols) -> out bf16 ld264 ----------------
__global__ __launch_bounds__(256) void gather_l2_kernel(
    const bf16* __restrict__ h1, const int* __restrict__ rowp, const int* __restrict__ adj,
    const float* __restrict__ gsum, bf16* __restrict__ out, int N)
{
    int n = blockIdx.x * 4 + (threadIdx.x >> 6);
    if (n >= N) return;
    int lane = threadIdx.x & 63;
    float a0 = 0.f, a1 = 0.f, b0 = 0.f, b1 = 0.f, cS = 0.f;
    int j0 = rowp[n], j1 = rowp[n + 1];
    for (int j = j0; j < j1; ++j) {
        int o = adj[j];
        const ushort2* hr = (const ushort2*)(h1 + (long)o * 264);
        ushort2 x = hr[lane];        // cols 2l, 2l+1
        ushort2 y = hr[64 + lane];   // cols 128+2l, 129+2l
        a0 += b2f(x.x); a1 += b2f(x.y);
        b0 += b2f(y.x); b1 += b2f(y.y);
        if (lane == 0) cS += __bfloat162float(h1[(long)o * 264 + 256]);
    }
    bf16* orow = out + (long)n * 264;
    ushort2 p0; p0.x = f2b(a0); p0.y = f2b(a1);
    ushort2 p1; p1.x = f2b(b0); p1.y = f2b(b1);
    ((ushort2*)orow)[lane] = p0;
    ((ushort2*)orow)[64 + lane] = p1;
    if (lane == 0) {
        orow[256] = __float2bfloat16(cS);
        orow[257] = __float2bfloat16(gsum[n]);
    } else if (lane < 4) {
        ushort2 z; z.x = 0; z.y = 0;
        ((ushort2*)orow)[128 + lane] = z;   // cols 258..263
    }
}

// ---------------- column stats over bf16 matrix ----------------
__global__ __launch_bounds__(256) void col_stats_b_kernel(
    const bf16* __restrict__ X, int ld, int Nrows, int F,
    float* __restrict__ sum, float* __restrict__ sumsq)
{
    int tid = threadIdx.x;
    int rpb = (Nrows + gridDim.x - 1) / gridDim.x;
    int r0 = blockIdx.x * rpb, r1 = min(Nrows, r0 + rpb);
    int c0 = tid, c1 = tid + 256;
    float s0 = 0.f, q0 = 0.f, s1 = 0.f, q1 = 0.f;
    for (int r = r0; r < r1; ++r) {
        const bf16* row = X + (long)r * ld;
        if (c0 < F) { float x = __bfloat162float(row[c0]); s0 += x; q0 += x * x; }
        if (c1 < F) { float x = __bfloat162float(row[c1]); s1 += x; q1 += x * x; }
    }
    if (c0 < F) { atomicAdd(&sum[c0], s0); atomicAdd(&sumsq[c0], q0); }
    if (c1 < F) { atomicAdd(&sum[c1], s1); atomicAdd(&sumsq[c1], q1); }
}

__global__ void bn_finalize_kernel(const float* __restrict__ sum, const float* __restrict__ sumsq,
                                   int F, float Nf, float* __restrict__ mean, float* __restrict__ scale)
{
    int c = blockIdx.x * blockDim.x + threadIdx.x;
    if (c < F) {
        float m = sum[c] / Nf;
        float var = sumsq[c] / Nf - m * m;
        mean[c] = m;
        scale[c] = 1.0f / sqrtf(var + BN_EPS);
    }
}

// ---------------- fold BN into w1 ----------------
__global__ __launch_bounds__(256) void wfold_kernel(
    const float* __restrict__ w, int Ktot, int M,
    const float* __restrict__ mean, const float* __restrict__ scale,
    int Kpad, int Mpad, bf16* __restrict__ wout, float* __restrict__ bias)
{
    __shared__ float sh[256];
    int m = blockIdx.x;
    int tid = threadIdx.x;
    float bs = 0.f;
    bf16* orow = wout + (long)m * Kpad;
    for (int k = tid; k < Kpad; k += 256) {
        float val = 0.f;
        if (m < M && k < Ktot) {
            float wv = w[(long)m * Ktot + k];
            val = wv * scale[k];
            bs -= mean[k] * scale[k] * wv;
        }
        orow[k] = __float2bfloat16(val);
    }
    sh[tid] = bs; __syncthreads();
    for (int st = 128; st > 0; st >>= 1) { if (tid < st) sh[tid] += sh[tid + st]; __syncthreads(); }
    if (tid == 0 && m < M) bias[m] = sh[0];
}

// ---------------- weight prep: remap [M][Ktot] f32 -> [Mpad][Kpad] bf16, virtual split ----------------
__global__ void wprep_kernel(const float* __restrict__ w, int Ktot, int M,
                             int K1, int W1, int K2, int Kpad, int Mpad,
                             bf16* __restrict__ out)
{
    int idx = blockIdx.x * 256 + threadIdx.x;
    if (idx >= Mpad * Kpad) return;
    int m = idx / Kpad, k = idx - m * Kpad;
    float val = 0.f;
    if (m < M) {
        if (k < W1) { if (k < K1) val = w[(long)m * Ktot + k]; }
        else { int j = k - W1; if (j < K2) val = w[(long)m * Ktot + K1 + j]; }
    }
    out[idx] = __float2bfloat16(val);
}

// ---------------- MFMA GEMM (1-D grid, col-fastest swizzle for A-row L2/L3 reuse) ----------------
template<typename CT>
__global__ __launch_bounds__(256) void mfma_gemm_kernel(
    const bf16* __restrict__ A0, int lda0, int W1,
    const bf16* __restrict__ A1, int lda1,
    const bf16* __restrict__ Wb, int Kpad,
    const float* __restrict__ bias,
    CT* __restrict__ C, long ldc, int Nrows, int M, int padlim, int relu, int gy)
{
    __shared__ bf16 sA[128 * 32];
    __shared__ bf16 sB[128 * 32];

    int tid  = threadIdx.x;
    int bid  = blockIdx.x;
    int row0 = (bid / gy) * 128;     // col varies fastest -> gy siblings share A row-tile
    int col0 = (bid % gy) * 128;
    int wave = tid >> 6, lane = tid & 63;
    int wr = (wave >> 1) * 64, wc = (wave & 1) * 64;
    int la = lane & 15, hk = lane >> 4;

    float4v acc[4][4];
    #pragma unroll
    for (int i = 0; i < 4; ++i)
        #pragma unroll
        for (int j = 0; j < 4; ++j)
            acc[i][j] = (float4v){0.f, 0.f, 0.f, 0.f};

    const short8v* sA8 = (const short8v*)sA;
    const short8v* sB8 = (const short8v*)sB;

    // hoisted per-thread staging addresses (2 chunks of 16B per tile)
    long offA0[2], offA1[2], offW[2];
    int  kq8_[2];
    char *ldsA_[2], *ldsB_[2];
    #pragma unroll
    for (int h = 0; h < 2; ++h) {
        int c = tid + h * 256;
        int r = c >> 2;
        int kq8 = (c & 3) * 8;
        kq8_[h] = kq8;
        int ga_row = row0 + r; if (ga_row >= Nrows) ga_row = Nrows - 1;
        offA0[h] = (long)ga_row * lda0 + kq8;
        offA1[h] = (long)ga_row * lda1 + kq8 - W1;
        offW[h]  = (long)(col0 + r) * Kpad + kq8;
        ldsA_[h] = (char*)sA + (size_t)c * 16;
        ldsB_[h] = (char*)sB + (size_t)c * 16;
    }

    for (int k0 = 0; k0 < Kpad; k0 += 32) {
        #pragma unroll
        for (int h = 0; h < 2; ++h) {
            int ka = k0 + kq8_[h];
            const bf16* gp = (ka < W1) ? (A0 + offA0[h] + k0) : (A1 + offA1[h] + k0);
            gload_lds16(gp, ldsA_[h]);
            gload_lds16(Wb + offW[h] + k0, ldsB_[h]);
        }
        __syncthreads();

        short8v afr[4], bfr[4];
        #pragma unroll
        for (int mf = 0; mf < 4; ++mf)
            afr[mf] = sA8[(size_t)(wr + mf * 16 + la) * 4 + hk];
        #pragma unroll
        for (int nf = 0; nf < 4; ++nf)
            bfr[nf] = sB8[(size_t)(wc + nf * 16 + la) * 4 + hk];
        #pragma unroll
        for (int mf = 0; mf < 4; ++mf)
            #pragma unroll
            for (int nf = 0; nf < 4; ++nf)
                acc[mf][nf] = __builtin_amdgcn_mfma_f32_16x16x32_bf16(
                    afr[mf], bfr[nf], acc[mf][nf], 0, 0, 0);
        __syncthreads();
    }

    #pragma unroll
    for (int mf = 0; mf < 4; ++mf) {
        #pragma unroll
        for (int r = 0; r < 4; ++r) {
            long grow = row0 + wr + mf * 16 + hk * 4 + r;
            if (grow >= Nrows) continue;
            #pragma unroll
            for (int nf = 0; nf < 4; ++nf) {
                int gcol = col0 + wc + nf * 16 + la;
                if (gcol >= padlim) continue;
                float vv = 0.f;
                if (gcol < M) {
                    vv = acc[mf][nf][r];
                    if (bias) vv += bias[gcol];
                    if (relu) vv = fmaxf(vv, 0.f);
                }
                stv(C, grow * ldc + gcol, vv);
            }
        }
    }
}

// ---------------- link head: gather hq rows, then MFMA, then dot ----------------
__global__ __launch_bounds__(256) void link_gather_kernel(
    const bf16* __restrict__ h2, const int* __restrict__ qu, const int* __restrict__ qv,
    bf16* __restrict__ hq)
{
    int q = blockIdx.x * 4 + (threadIdx.x >> 6);
    if (q >= QQ) return;
    int lane = threadIdx.x & 63;
    const ushort4* ra4 = (const ushort4*)(h2 + (long)qu[q] * 520);  // 130 x 8B
    const ushort4* rb4 = (const ushort4*)(h2 + (long)qv[q] * 520);
    ushort4* o4 = (ushort4*)(hq + (long)q * 1056);                  // 264 x 8B
    #pragma unroll 3
    for (int k = lane; k < 130; k += 64) o4[k] = ra4[k];
    #pragma unroll 3
    for (int k = lane; k < 130; k += 64) o4[130 + k] = rb4[k];
    if (lane < 4) { ushort4 z; z.x = z.y = z.z = z.w = 0; o4[260 + lane] = z;}  // cols 1040..1055
}

__global__ __launch_bounds__(256) void link_dot_kernel(
    const float* __restrict__ tmpl, const float* __restrict__ link_o, float* __restrict__ out)
{
    int q = blockIdx.x * 4 + (threadIdx.x >> 6);
    if (q >= QQ) return;
    int lane = threadIdx.x & 63;
    const float* r = tmpl + (long)q * 128;
    float s = r[lane] * link_o[lane] + r[lane + 64] * link_o[lane + 64];
    #pragma unroll
    for (int off = 32; off > 0; off >>= 1) s += __shfl_xor(s, off, 64);
    if (lane == 0) out[q] = s;
}

// ---------------- fallback-path kernels (round-1 tier-B, proven) ----------------
template<typename HT>
__global__ __launch_bounds__(256) void scatter_edges_kernel(
    const HT* __restrict__ h, int ldh, int P,
    const int* __restrict__ u, const int* __restrict__ v,
    const float* __restrict__ t, int E,
    float* __restrict__ agg, int lda)
{
    long gid = (long)blockIdx.x * blockDim.x + threadIdx.x;
    int e = (int)(gid >> 6);
    int lane = (int)(gid & 63);
    if (e >= E) return;
    int uu = u[e], vv = v[e];
    float tlast = t[E - 1], tfirst = t[0];
    float ge = (tlast - t[e]) / (1.0f + tlast - tfirst);
    const HT* hu = h + (long)uu * ldh;
    const HT* hv = h + (long)vv * ldh;
    float* au = agg + (long)uu * lda;
    float* av = agg + (long)vv * lda;
    for (int f = lane; f < P; f += 64) {
        atomicAdd(&av[f], ldv(hu, f));
        atomicAdd(&au[f], ldv(hv, f));
    }
    if (lane == 0) {
        atomicAdd(&av[P], ge);
        atomicAdd(&au[P], ge);
    }
}

__global__ __launch_bounds__(256) void col_stats_kernel(
    const float* __restrict__ X, int Nrows, int F,
    float* __restrict__ sum, float* __restrict__ sumsq)
{
    int tid = threadIdx.x;
    int rowsPerBlock = (Nrows + gridDim.x - 1) / gridDim.x;
    int r0 = blockIdx.x * rowsPerBlock;
    int r1 = min(Nrows, r0 + rowsPerBlock);
    int c0 = tid, c1 = tid + 256;
    float s0 = 0.f, q0 = 0.f, s1 = 0.f, q1 = 0.f;
    for (int r = r0; r < r1; ++r) {
        const float* row = X + (long)r * F;
        if (c0 < F) { float x = row[c0]; s0 += x; q0 += x * x; }
        if (c1 < F) { float x = row[c1]; s1 += x; q1 += x * x; }
    }
    if (c0 < F) { atomicAdd(&sum[c0], s0); atomicAdd(&sumsq[c0], q0); }
    if (c1 < F) { atomicAdd(&sum[c1], s1); atomicAdd(&sumsq[c1], q1); }
}

#define BM 64
#define BNT 64
#define BK 32
template<typename AT0, typename AT1, typename CT>
__global__ __launch_bounds__(256) void gemm_kernel(
    const AT0* __restrict__ A0, int lda0, int cols0,
    const AT1* __restrict__ A1, int lda1,
    const float* __restrict__ Bw,
    CT* __restrict__ C, int ldc,
    int Nrows, int K, int M,
    const float* __restrict__ bn_mean, const float* __restrict__ bn_scale,
    int relu)
{
    __shared__ float sA[BM][BK + 1];
    __shared__ float sB[BNT][BK + 1];
    int row0 = blockIdx.x * BM;
    int col0 = blockIdx.y * BNT;
    int tid = threadIdx.x;
    int tx = tid & 15, ty = tid >> 4;
    float acc[4][4] = {{0.f}};
    for (int k0 = 0; k0 < K; k0 += BK) {
        int i = tid >> 2;
        int j = (tid & 3) * 8;
        int gr = row0 + i;
        int gm = col0 + i;
        #pragma unroll
        for (int s = 0; s < 8; ++s) {
            int gk = k0 + j + s;
            float val = 0.f;
            if (gr < Nrows && gk < K) {
                if (gk < cols0) val = ldv(A0, (long)gr * lda0 + gk);
                else            val = ldv(A1, (long)gr * lda1 + (gk - cols0));
                if (bn_mean) val = (val - bn_mean[gk]) * bn_scale[gk];
            }
            sA[i][j + s] = val;
            float bv = 0.f;
            if (gm < M && gk < K) bv = Bw[(long)gm * K + gk];
            sB[i][j + s] = bv;
        }
        __syncthreads();
        #pragma unroll
        for (int kk = 0; kk < BK; ++kk) {
            float a[4], b[4];
            #pragma unroll
            for (int r = 0; r < 4; ++r) a[r] = sA[ty * 4 + r][kk];
            #pragma unroll
            for (int c = 0; c < 4; ++c) b[c] = sB[tx * 4 + c][kk];
            #pragma unroll
            for (int r = 0; r < 4; ++r)
                #pragma unroll
                for (int c = 0; c < 4; ++c)
                    acc[r][c] += a[r] * b[c];
        }
        __syncthreads();
    }
    #pragma unroll
    for (int r = 0; r < 4; ++r) {
        int gr = row0 + ty * 4 + r;
        if (gr >= Nrows) continue;
        #pragma unroll
        for (int c = 0; c < 4; ++c) {
            int gm = col0 + tx * 4 + c;
            if (gm >= M) continue;
            float vv = acc[r][c];
            if (relu) vv = fmaxf(vv, 0.f);
            stv(C, (long)gr * ldc + gm, vv);
        }
    }
}

// ---------------- legacy link head (fallback path) ----------------
template<typename HT>
__global__ __launch_bounds__(128) void link_kernel(
    const HT* __restrict__ h2, int ldh,
    const int* __restrict__ qu, const int* __restrict__ qv,
    const float* __restrict__ link_h,
    const float* __restrict__ link_o,
    float* __restrict__ out)
{
    __shared__ float sh[1030];
    __shared__ float red[128];
    int q = blockIdx.x;
    int tid = threadIdx.x;
    int a = qu[q], b = qv[q];
    for (int k = tid; k < 515; k += 128) sh[k] = ldv(h2, (long)a * ldh + k);
    for (int k = tid; k < 515; k += 128) sh[515 + k] = ldv(h2, (long)b * ldh + k);
    __syncthreads();
    const float* wrow = link_h + (long)tid * 1030;
    float y = 0.f;
    for (int k = 0; k < 1030; ++k) y += sh[k] * wrow[k];
    y = fmaxf(y, 0.f) * link_o[tid];
    red[tid] = y;
    __syncthreads();
    for (int s = 64; s > 0; s >>= 1) {
        if (tid < s) red[tid] += red[tid + s];
        __syncthreads();
    }
    if (tid == 0) out[q] = red[0];
}

// ---------------- launch ----------------
extern "C" void kernel_launch(void* const* d_in, const int* in_sizes, int n_in,
                              void* d_out, int out_size, void* d_ws, size_t ws_size,
                              hipStream_t stream)
{
    const int*   u      = (const int*)d_in[0];
    const int*   v      = (const int*)d_in[1];
    const float* t      = (const float*)d_in[2];
    const int*   qu     = (const int*)d_in[3];
    const int*   qv     = (const int*)d_in[4];
    const float* h0     = (const float*)d_in[5];
    const float* w1_0   = (const float*)d_in[6];
    const float* w2_0   = (const float*)d_in[7];
    const float* w1_1   = (const float*)d_in[8];
    const float* w2_1   = (const float*)d_in[9];
    const float* link_h = (const float*)d_in[10];
    const float* link_o = (const float*)d_in[11];
    const float* node_h = (const float*)d_in[12];
    const float* node_o = (const float*)d_in[13];

    float* out_link = (float*)d_out;
    float* out_node = (float*)d_out + QQ;

    char* wsb = (char*)d_ws;

    float* stats = (float*)wsb;  // 4096 floats
    float* sum1 = stats,         * sumsq1 = stats + 512;
    float* mean1 = stats + 1024, * scale1 = stats + 1536;
    float* sum2 = stats + 2048,  * sumsq2 = stats + 2560;
    float* mean2 = stats + 3072, * scale2 = stats + 3584;

    if (ws_size >= 217000000ull) {
        // ================= FAST: CSR-gather + full-MFMA path (216.1 MB) =================
        // weights
        bf16* wf1_0 = (bf16*)(wsb + 16384);        // 256 x 160 (BN-folded, runtime)
        bf16* wb2_0 = (bf16*)(wsb + 98304);        // 384 x 288
        bf16* wf1_1 = (bf16*)(wsb + 319488);       // 384 x 288 (BN-folded, runtime)
        bf16* wb2_1 = (bf16*)(wsb + 540672);       // 640 x 544
        bf16* wbnh  = (bf16*)(wsb + 1236992);      // 128 x 544
        bf16* wbno  = (bf16*)(wsb + 1376256);      // 128 x 128
        float* bias1 = (float*)(wsb + 1409024);    // 256
        float* bias2 = (float*)(wsb + 1410048);    // 512
        // CSR
        float* gsum = (float*)(wsb + 1412096);     // N
        int*   deg  = (int*)  (wsb + 1812096);     // N   (gsum+deg zeroed together)
        int*   rowp = (int*)  (wsb + 2212096);     // N+1
        int*   cur  = (int*)  (wsb + 2612104);     // N
        int*   bsum = (int*)  (wsb + 3012104);     // 256
        int*   boff = (int*)  (wsb + 3013128);     // 256
        int*   adj  = (int*)  (wsb + 3016200);     // 2E ints -> ends 6216200
        bf16*  wlk  = (bf16*) (wsb + 6220000);     // 128 x 1056 link weight
        // big regions
        bf16* h1   = (bf16*)(wsb + 6500000ull);    // A: N x 264                [6.5M, 59.3M)
        bf16* tmpb = (bf16*)(wsb + 6500000ull);    //    node hidden (aliases A after h2-gemm)
        bf16* z0   = (bf16*)(wsb + 59300000ull);   // C: N x 136
        bf16* h0b  = (bf16*)(wsb + 86500000ull);   //    N x 128
        bf16* z1   = (bf16*)(wsb + 59300000ull);   //    N x 264 (C reused)     [59.3M, 112.1M)
        bf16* hq   = (bf16*)(wsb + 59300000ull);   //    Q x 1056 (C reused after h2-gemm)
        float* tmpl = (float*)(wsb + 70000000ull); //    Q x 128 f32 link hidden
        bf16* aggb = (bf16*)(wsb + 112100000ull);  // B: N x 136 / N x 264      [112.1M, 164.9M)
        bf16* h2   = (bf16*)(wsb + 112100000ull);  // D: N x 520 (aliases B after z1-gemm) [112.1M, 216.1M)

        const int gx = (NN + 127) / 128;           // 782
        const int chunk = (NN + NCHUNK - 1) / NCHUNK;  // 391

        // zero stats + gsum/deg
        zero_kernel<<<16, 256, 0, stream>>>(stats, 4096);
        zero_kernel<<<64, 256, 0, stream>>>(gsum, 200000);  // gsum(100k) + deg(100k) contiguous

        // static weight prep
        wprep_kernel<<<432, 256, 0, stream>>>(w2_0, 257, 257, 128, 128, 129, 288, 384, wb2_0);
        wprep_kernel<<<1360, 256, 0, stream>>>(w2_1, 515, 515, 257, 272, 258, 544, 640, wb2_1);
        wprep_kernel<<<272, 256, 0, stream>>>(node_h, 515, 128, 515, 544, 0, 544, 128, wbnh);
        wprep_kernel<<<64, 256, 0, stream>>>(node_o, 128, 10, 128, 128, 0, 128, 128, wbno);
        wprep_kernel<<<528, 256, 0, stream>>>(link_h, 1030, 128, 515, 520, 515, 1056, 128, wlk);
        // h0 -> bf16 early (gather_l1 consumes bf16 now)
        wprep_kernel<<<50000, 256, 0, stream>>>(h0, 128, NN, 128, 128, 0, 128, NN, h0b);

        // CSR build (shared by both layers)
        csr_count_kernel<<<(EE + 255) / 256, 256, 0, stream>>>(u, v, EE, deg);
        csr_chunksum_kernel<<<NCHUNK, 256, 0, stream>>>(deg, NN, chunk, bsum);
        csr_scanb_kernel<<<1, 64, 0, stream>>>(bsum, boff);
        csr_rowp_kernel<<<NCHUNK, 64, 0, stream>>>(deg, boff, NN, chunk, rowp, cur);
        csr_fill_kernel<<<(EE + 255) / 256, 256, 0, stream>>>(u, v, t, EE, cur, adj, gsum);

        // ---- layer 1 ----
        gather_l1_kernel<<<NN / 4, 256, 0, stream>>>(h0b, rowp, adj, gsum, aggb, NN);
        col_stats_b_kernel<<<512, 256, 0, stream>>>(aggb, 136, NN, 129, sum1, sumsq1);
        bn_finalize_kernel<<<2, 256, 0, stream>>>(sum1, sumsq1, 129, (float)NN, mean1, scale1);
        wfold_kernel<<<256, 256, 0, stream>>>(w1_0, 129, 129, mean1, scale1, 160, 256, wf1_0, bias1);
        // z0 = relu(aggb @ wf1_0^T + bias1)
        mfma_gemm_kernel<bf16><<<gx * 2, 256, 0, stream>>>(
            aggb, 136, 160, aggb, 136, wf1_0, 160, bias1, z0, 136, NN, 129, 136, 1, 2);
        // h1 = [h0b | z0] @ wb2_0^T
        mfma_gemm_kernel<bf16><<<gx * 3, 256, 0, stream>>>(
            h0b, 128, 128, z0, 136, wb2_0, 288, nullptr, h1, 264, NN, 257, 264, 0, 3);

        // ---- layer 2 ----
        gather_l2_kernel<<<NN / 4, 256, 0, stream>>>(h1, rowp, adj, gsum, aggb, NN);
        col_stats_b_kernel<<<512, 256, 0, stream>>>(aggb, 264, NN, 258, sum2, sumsq2);
        bn_finalize_kernel<<<2, 256, 0, stream>>>(sum2, sumsq2, 258, (float)NN, mean2, scale2);
        wfold_kernel<<<384, 256, 0, stream>>>(w1_1, 258, 258, mean2, scale2, 288, 384, wf1_1, bias2);
        // z1 = relu(aggb @ wf1_1^T + bias2)
        mfma_gemm_kernel<bf16><<<gx * 3, 256, 0, stream>>>(
            aggb, 264, 288, aggb, 264, wf1_1, 288, bias2, z1, 264, NN, 258, 264, 1, 3);
        // h2 = [h1 | z1] @ wb2_1^T   (writes D; B dead)
        mfma_gemm_kernel<bf16><<<gx * 5, 256, 0, stream>>>(
            h1, 264, 272, z1, 264, wb2_1, 544, nullptr, h2, 520, NN, 515, 520, 0, 5);

        // ---- node head (MFMA) ----
        mfma_gemm_kernel<bf16><<<gx, 256, 0, stream>>>(
            h2, 520, 544, h2, 520, wbnh, 544, nullptr, tmpb, 128, NN, 128, 128, 1, 1);
        mfma_gemm_kernel<float><<<gx, 256, 0, stream>>>(
            tmpb, 128, 128, tmpb, 128, wbno, 128, nullptr, out_node, CLASSES, NN, 10, 10, 0, 1);

        // ---- link head: gather -> MFMA -> dot ----
        link_gather_kernel<<<QQ / 4, 256, 0, stream>>>(h2, qu, qv, hq);
        mfma_gemm_kernel<float><<<QQ / 128, 256, 0, stream>>>(
            hq, 1056, 1056, hq, 1056, wlk, 1056, nullptr, tmpl, 128, QQ, 128, 128, 1, 1);
        link_dot_kernel<<<QQ / 4, 256, 0, stream>>>(tmpl, link_o, out_link);
    } else {
        // ================= FALLBACK: round-1 tier-B (proven) =================
        const int gx = (NN + BM - 1) / BM;
        const int scatter_blocks = (EE * 64 + 255) / 256;
        float* agg = (float*)(wsb + 16384);
        bf16*  h2b = (bf16*) (wsb + 16384);
        bf16*  h1b = (bf16*) (wsb + 16384 + 103200000ull);
        bf16*  zb  = (bf16*) (wsb + 16384 + 154600000ull);
        float* tmp = (float*)(wsb + 16384 + 154600000ull);

        zero_kernel<<<16, 256, 0, stream>>>(stats, 4096);

        zero_kernel<<<2048, 256, 0, stream>>>(agg, (size_t)NN * 129);
        scatter_edges_kernel<float><<<scatter_blocks, 256, 0, stream>>>(
            h0, 128, 128, u, v, t, EE, agg, 129);
        col_stats_kernel<<<512, 256, 0, stream>>>(agg, NN, 129, sum1, sumsq1);
        bn_finalize_kernel<<<2, 256, 0, stream>>>(sum1, sumsq1, 129, (float)NN, mean1, scale1);
        gemm_kernel<float, float, bf16><<<dim3(gx, 3), 256, 0, stream>>>(
            agg, 129, 129, (const float*)nullptr, 0, w1_0, zb, 129, NN, 129, 129, mean1, scale1, 1);
        gemm_kernel<float, bf16, bf16><<<dim3(gx, 5), 256, 0, stream>>>(
            h0, 128, 128, zb, 129, w2_0, h1b, 257, NN, 257, 257, nullptr, nullptr, 0);

        zero_kernel<<<2048, 256, 0, stream>>>(agg, (size_t)NN * 258);
        scatter_edges_kernel<bf16><<<scatter_blocks, 256, 0, stream>>>(
            h1b, 257, 257, u, v, t, EE, agg, 258);
        col_stats_kernel<<<512, 256, 0, stream>>>(agg, NN, 258, sum2, sumsq2);
        bn_finalize_kernel<<<2, 256, 0, stream>>>(sum2, sumsq2, 258, (float)NN, mean2, scale2);
        gemm_kernel<float, float, bf16><<<dim3(gx, 5), 256, 0, stream>>>(
            agg, 258, 258, (const float*)nullptr, 0, w1_1, zb, 258, NN, 258, 258, mean2, scale2, 1);
        gemm_kernel<bf16, bf16, bf16><<<dim3(gx, 9), 256, 0, stream>>>(
            h1b, 257, 257, zb, 258, w2_1, h2b, 515, NN, 515, 515, nullptr, nullptr, 0);

        gemm_kernel<bf16, float, float><<<dim3(gx, 2), 256, 0, stream>>>(
            h2b, 515, 515, (const float*)nullptr, 0, node_h, tmp, 128, NN, 515, 128, nullptr, nullptr, 1);
        gemm_kernel<float, float, float><<<dim3(gx, 1), 256, 0, stream>>>(
            tmp, 128, 128, tmp, 128, node_o, out_node, CLASSES, NN, 128, CLASSES, nullptr, nullptr, 0);

        link_kernel<bf16><<<QQ, 128, 0, stream>>>(h2b, 515, qu, qv, link_h, link_o, out_link);
    }
}

// Round 8
// 1065.839 us; speedup vs baseline: 1.0382x; 1.0382x over previous
//
#include <hip/hip_runtime.h>
#include <hip/hip_bf16.h>

#define NN      100000
#define EE      400000
#define QQ      4096
#define CLASSES 10
#define BN_EPS  1e-5f
#define NCHUNK  256

typedef __hip_bfloat16 bf16;
typedef __attribute__((ext_vector_type(8))) short short8v;
typedef __attribute__((ext_vector_type(4))) float float4v;

__device__ inline float ldv(const float* p, long i) { return p[i]; }
__device__ inline float ldv(const bf16*  p, long i) { return __bfloat162float(p[i]); }
__device__ inline void  stv(float* p, long i, float v) { p[i] = v; }
__device__ inline void  stv(bf16*  p, long i, float v) { p[i] = __float2bfloat16(v); }

__device__ inline unsigned short f2b(float f) { bf16 b = __float2bfloat16(f); unsigned short s; __builtin_memcpy(&s, &b, 2); return s; }
__device__ inline float b2f(unsigned short s) { bf16 b; __builtin_memcpy(&b, &s, 2); return __bfloat162float(b); }

__device__ __forceinline__ void gload_lds16(const void* g, void* l) {
    __builtin_amdgcn_global_load_lds(
        (const __attribute__((address_space(1))) void*)g,
        (__attribute__((address_space(3))) void*)l,
        16, 0, 0);
}

// ---------------- zeroing ----------------
__global__ void zero_kernel(float* __restrict__ p, size_t n) {
    size_t i  = (size_t)blockIdx.x * blockDim.x + threadIdx.x;
    size_t st = (size_t)gridDim.x * blockDim.x;
    for (; i < n; i += st) p[i] = 0.f;
}

// ---------------- CSR build ----------------
__global__ void csr_count_kernel(const int* __restrict__ u, const int* __restrict__ v, int E, int* __restrict__ deg) {
    int e = blockIdx.x * 256 + threadIdx.x;
    if (e < E) { atomicAdd(&deg[u[e]], 1); atomicAdd(&deg[v[e]], 1); }
}

__global__ __launch_bounds__(256) void csr_chunksum_kernel(const int* __restrict__ deg, int N, int chunk, int* __restrict__ bsum) {
    __shared__ int sh[256];
    int b = blockIdx.x, tid = threadIdx.x;
    int i0 = b * chunk, i1 = min(N, i0 + chunk);
    int s = 0;
    for (int i = i0 + tid; i < i1; i += 256) s += deg[i];
    sh[tid] = s; __syncthreads();
    for (int st = 128; st > 0; st >>= 1) { if (tid < st) sh[tid] += sh[tid + st]; __syncthreads(); }
    if (tid == 0) bsum[b] = sh[0];
}

__global__ void csr_scanb_kernel(const int* __restrict__ bsum, int* __restrict__ boff) {
    if (threadIdx.x == 0 && blockIdx.x == 0) {
        int r = 0;
        for (int i = 0; i < NCHUNK; ++i) { boff[i] = r; r += bsum[i]; }
    }
}

__global__ void csr_rowp_kernel(const int* __restrict__ deg, const int* __restrict__ boff,
                                int N, int chunk, int* __restrict__ rowp, int* __restrict__ cur) {
    int b = blockIdx.x;
    if (threadIdx.x != 0) return;
    int i0 = b * chunk, i1 = min(N, i0 + chunk);
    int r = boff[b];
    for (int i = i0; i < i1; ++i) { rowp[i] = r; cur[i] = r; r += deg[i]; }
    if (b == NCHUNK - 1) rowp[N] = r;
}

__global__ void csr_fill_kernel(const int* __restrict__ u, const int* __restrict__ v,
                                const float* __restrict__ t, int E,
                                int* __restrict__ cur, int* __restrict__ adj, float* __restrict__ gsum) {
    int e = blockIdx.x * 256 + threadIdx.x;
    if (e >= E) return;
    int a = u[e], b = v[e];
    float tlast = t[E - 1], tfirst = t[0];
    float ge = (tlast - t[e]) / (1.0f + tlast - tfirst);
    int p = atomicAdd(&cur[a], 1); adj[p] = b;
    int q = atomicAdd(&cur[b], 1); adj[q] = a;
    atomicAdd(&gsum[a], ge); atomicAdd(&gsum[b], ge);
}

// ---------------- gather L1 (bf16 input) ----------------
__global__ __launch_bounds__(256) void gather_l1_kernel(
    const bf16* __restrict__ h0b, const int* __restrict__ rowp, const int* __restrict__ adj,
    const float* __restrict__ gsum, bf16* __restrict__ out, int N)
{
    int n = blockIdx.x * 4 + (threadIdx.x >> 6);
    if (n >= N) return;
    int lane = threadIdx.x & 63;
    float a0 = 0.f, a1 = 0.f;
    int j0 = rowp[n], j1 = rowp[n + 1];
    for (int j = j0; j < j1; ++j) {
        int o = adj[j];
        ushort2 x = ((const ushort2*)(h0b + (long)o * 128))[lane];
        a0 += b2f(x.x); a1 += b2f(x.y);
    }
    bf16* orow = out + (long)n * 136;
    ushort2 pv; pv.x = f2b(a0); pv.y = f2b(a1);
    ((ushort2*)orow)[lane] = pv;
    if (lane == 0) {
        orow[128] = __float2bfloat16(gsum[n]);
        orow[129] = __float2bfloat16(0.f);
    } else if (lane < 4) {
        ushort2 z; z.x = 0; z.y = 0;
        ((ushort2*)(orow + 130))[lane - 1] = z;   // cols 130..135
    }
}

// ---------------- gather L2 ----------------
__global__ __launch_bounds__(256) void gather_l2_kernel(
    const bf16* __restrict__ h1, const int* __restrict__ rowp, const int* __restrict__ adj,
    const float* __restrict__ gsum, bf16* __restrict__ out, int N)
{
    int n = blockIdx.x * 4 + (threadIdx.x >> 6);
    if (n >= N) return;
    int lane = threadIdx.x & 63;
    float a0 = 0.f, a1 = 0.f, b0 = 0.f, b1 = 0.f, cS = 0.f;
    int j0 = rowp[n], j1 = rowp[n + 1];
    for (int j = j0; j < j1; ++j) {
        int o = adj[j];
        const ushort2* hr = (const ushort2*)(h1 + (long)o * 264);
        ushort2 x = hr[lane];
        ushort2 y = hr[64 + lane];
        a0 += b2f(x.x); a1 += b2f(x.y);
        b0 += b2f(y.x); b1 += b2f(y.y);
        if (lane == 0) cS += __bfloat162float(h1[(long)o * 264 + 256]);
    }
    bf16* orow = out + (long)n * 264;
    ushort2 p0; p0.x = f2b(a0); p0.y = f2b(a1);
    ushort2 p1; p1.x = f2b(b0); p1.y = f2b(b1);
    ((ushort2*)orow)[lane] = p0;
    ((ushort2*)orow)[64 + lane] = p1;
    if (lane == 0) {
        orow[256] = __float2bfloat16(cS);
        orow[257] = __float2bfloat16(gsum[n]);
    } else if (lane < 4) {
        ushort2 z; z.x = 0; z.y = 0;
        ((ushort2*)orow)[128 + lane] = z;   // cols 258..263
    }
}

// ---------------- column stats over bf16 matrix ----------------
__global__ __launch_bounds__(256) void col_stats_b_kernel(
    const bf16* __restrict__ X, int ld, int Nrows, int F,
    float* __restrict__ sum, float* __restrict__ sumsq)
{
    int tid = threadIdx.x;
    int rpb = (Nrows + gridDim.x - 1) / gridDim.x;
    int r0 = blockIdx.x * rpb, r1 = min(Nrows, r0 + rpb);
    int c0 = tid, c1 = tid + 256;
    float s0 = 0.f, q0 = 0.f, s1 = 0.f, q1 = 0.f;
    for (int r = r0; r < r1; ++r) {
        const bf16* row = X + (long)r * ld;
        if (c0 < F) { float x = __bfloat162float(row[c0]); s0 += x; q0 += x * x; }
        if (c1 < F) { float x = __bfloat162float(row[c1]); s1 += x; q1 += x * x; }
    }
    if (c0 < F) { atomicAdd(&sum[c0], s0); atomicAdd(&sumsq[c0], q0); }
    if (c1 < F) { atomicAdd(&sum[c1], s1); atomicAdd(&sumsq[c1], q1); }
}

__global__ void bn_finalize_kernel(const float* __restrict__ sum, const float* __restrict__ sumsq,
                                   int F, float Nf, float* __restrict__ mean, float* __restrict__ scale)
{
    int c = blockIdx.x * blockDim.x + threadIdx.x;
    if (c < F) {
        float m = sum[c] / Nf;
        float var = sumsq[c] / Nf - m * m;
        mean[c] = m;
        scale[c] = 1.0f / sqrtf(var + BN_EPS);
    }
}

// ---------------- fold BN into w1 ----------------
__global__ __launch_bounds__(256) void wfold_kernel(
    const float* __restrict__ w, int Ktot, int M,
    const float* __restrict__ mean, const float* __restrict__ scale,
    int Kpad, int Mpad, bf16* __restrict__ wout, float* __restrict__ bias)
{
    __shared__ float sh[256];
    int m = blockIdx.x;
    int tid = threadIdx.x;
    float bs = 0.f;
    bf16* orow = wout + (long)m * Kpad;
    for (int k = tid; k < Kpad; k += 256) {
        float val = 0.f;
        if (m < M && k < Ktot) {
            float wv = w[(long)m * Ktot + k];
            val = wv * scale[k];
            bs -= mean[k] * scale[k] * wv;
        }
        orow[k] = __float2bfloat16(val);
    }
    sh[tid] = bs; __syncthreads();
    for (int st = 128; st > 0; st >>= 1) { if (tid < st) sh[tid] += sh[tid + st]; __syncthreads(); }
    if (tid == 0 && m < M) bias[m] = sh[0];
}

// ---------------- weight prep ----------------
__global__ void wprep_kernel(const float* __restrict__ w, int Ktot, int M,
                             int K1, int W1, int K2, int Kpad, int Mpad,
                             bf16* __restrict__ out)
{
    int idx = blockIdx.x * 256 + threadIdx.x;
    if (idx >= Mpad * Kpad) return;
    int m = idx / Kpad, k = idx - m * Kpad;
    float val = 0.f;
    if (m < M) {
        if (k < W1) { if (k < K1) val = w[(long)m * Ktot + k]; }
        else { int j = k - W1; if (j < K2) val = w[(long)m * Ktot + K1 + j]; }
    }
    out[idx] = __float2bfloat16(val);
}

// ---------------- MFMA GEMM (XCD-aware bijective swizzle; col-fastest works) ----------------
// Work w = row*gy + col. bid->wgid maps each XCD (bid%8, HW round-robin) to a
// contiguous work chunk, so all gy col-siblings of a row-tile share one L2.
template<typename CT>
__global__ __launch_bounds__(256) void mfma_gemm_kernel(
    const bf16* __restrict__ A0, int lda0, int W1,
    const bf16* __restrict__ A1, int lda1,
    const bf16* __restrict__ Wb, int Kpad,
    const float* __restrict__ bias,
    CT* __restrict__ C, long ldc, int Nrows, int M, int padlim, int relu, int gy)
{
    __shared__ bf16 sA[128 * 32];
    __shared__ bf16 sB[128 * 32];

    int tid  = threadIdx.x;
    int bid  = blockIdx.x;
    int nwg  = gridDim.x;
    // m204 bijective XCD swizzle
    int q    = nwg >> 3, rem = nwg & 7;
    int xcd  = bid & 7;
    int base = (xcd < rem) ? xcd * (q + 1) : rem * (q + 1) + (xcd - rem) * q;
    int wgid = base + (bid >> 3);
    int row0 = (wgid / gy) * 128;
    int col0 = (wgid % gy) * 128;

    int wave = tid >> 6, lane = tid & 63;
    int wr = (wave >> 1) * 64, wc = (wave & 1) * 64;
    int la = lane & 15, hk = lane >> 4;

    float4v acc[4][4];
    #pragma unroll
    for (int i = 0; i < 4; ++i)
        #pragma unroll
        for (int j = 0; j < 4; ++j)
            acc[i][j] = (float4v){0.f, 0.f, 0.f, 0.f};

    const short8v* sA8 = (const short8v*)sA;
    const short8v* sB8 = (const short8v*)sB;

    // hoisted per-thread staging addresses (2 chunks of 16B per tile)
    long offA0[2], offA1[2], offW[2];
    int  kq8_[2];
    char *ldsA_[2], *ldsB_[2];
    #pragma unroll
    for (int h = 0; h < 2; ++h) {
        int c = tid + h * 256;
        int r = c >> 2;
        int kq8 = (c & 3) * 8;
        kq8_[h] = kq8;
        int ga_row = row0 + r; if (ga_row >= Nrows) ga_row = Nrows - 1;
        offA0[h] = (long)ga_row * lda0 + kq8;
        offA1[h] = (long)ga_row * lda1 + kq8 - W1;
        offW[h]  = (long)(col0 + r) * Kpad + kq8;
        ldsA_[h] = (char*)sA + (size_t)c * 16;
        ldsB_[h] = (char*)sB + (size_t)c * 16;
    }

    for (int k0 = 0; k0 < Kpad; k0 += 32) {
        #pragma unroll
        for (int h = 0; h < 2; ++h) {
            int ka = k0 + kq8_[h];
            const bf16* gp = (ka < W1) ? (A0 + offA0[h] + k0) : (A1 + offA1[h] + k0);
            gload_lds16(gp, ldsA_[h]);
            gload_lds16(Wb + offW[h] + k0, ldsB_[h]);
        }
        __syncthreads();

        short8v afr[4], bfr[4];
        #pragma unroll
        for (int mf = 0; mf < 4; ++mf)
            afr[mf] = sA8[(size_t)(wr + mf * 16 + la) * 4 + hk];
        #pragma unroll
        for (int nf = 0; nf < 4; ++nf)
            bfr[nf] = sB8[(size_t)(wc + nf * 16 + la) * 4 + hk];
        #pragma unroll
        for (int mf = 0; mf < 4; ++mf)
            #pragma unroll
            for (int nf = 0; nf < 4; ++nf)
                acc[mf][nf] = __builtin_amdgcn_mfma_f32_16x16x32_bf16(
                    afr[mf], bfr[nf], acc[mf][nf], 0, 0, 0);
        __syncthreads();
    }

    #pragma unroll
    for (int mf = 0; mf < 4; ++mf) {
        #pragma unroll
        for (int r = 0; r < 4; ++r) {
            long grow = row0 + wr + mf * 16 + hk * 4 + r;
            if (grow >= Nrows) continue;
            #pragma unroll
            for (int nf = 0; nf < 4; ++nf) {
                int gcol = col0 + wc + nf * 16 + la;
                if (gcol >= padlim) continue;
                float vv = 0.f;
                if (gcol < M) {
                    vv = acc[mf][nf][r];
                    if (bias) vv += bias[gcol];
                    if (relu) vv = fmaxf(vv, 0.f);
                }
                stv(C, grow * ldc + gcol, vv);
            }
        }
    }
}

// ---------------- link head: gather hq rows, then MFMA, then dot ----------------
__global__ __launch_bounds__(256) void link_gather_kernel(
    const bf16* __restrict__ h2, const int* __restrict__ qu, const int* __restrict__ qv,
    bf16* __restrict__ hq)
{
    int q = blockIdx.x * 4 + (threadIdx.x >> 6);
    if (q >= QQ) return;
    int lane = threadIdx.x & 63;
    const ushort4* ra4 = (const ushort4*)(h2 + (long)qu[q] * 520);
    const ushort4* rb4 = (const ushort4*)(h2 + (long)qv[q] * 520);
    ushort4* o4 = (ushort4*)(hq + (long)q * 1056);
    #pragma unroll 3
    for (int k = lane; k < 130; k += 64) o4[k] = ra4[k];
    #pragma unroll 3
    for (int k = lane; k < 130; k += 64) o4[130 + k] = rb4[k];
    if (lane < 4) { ushort4 z; z.x = z.y = z.z = z.w = 0; o4[260 + lane] = z; }
}

__global__ __launch_bounds__(256) void link_dot_kernel(
    const float* __restrict__ tmpl, const float* __restrict__ link_o, float* __restrict__ out)
{
    int q = blockIdx.x * 4 + (threadIdx.x >> 6);
    if (q >= QQ) return;
    int lane = threadIdx.x & 63;
    const float* r = tmpl + (long)q * 128;
    float s = r[lane] * link_o[lane] + r[lane + 64] * link_o[lane + 64];
    #pragma unroll
    for (int off = 32; off > 0; off >>= 1) s += __shfl_xor(s, off, 64);
    if (lane == 0) out[q] = s;
}

// ---------------- fallback-path kernels (round-1 tier-B, proven) ----------------
template<typename HT>
__global__ __launch_bounds__(256) void scatter_edges_kernel(
    const HT* __restrict__ h, int ldh, int P,
    const int* __restrict__ u, const int* __restrict__ v,
    const float* __restrict__ t, int E,
    float* __restrict__ agg, int lda)
{
    long gid = (long)blockIdx.x * blockDim.x + threadIdx.x;
    int e = (int)(gid >> 6);
    int lane = (int)(gid & 63);
    if (e >= E) return;
    int uu = u[e], vv = v[e];
    float tlast = t[E - 1], tfirst = t[0];
    float ge = (tlast - t[e]) / (1.0f + tlast - tfirst);
    const HT* hu = h + (long)uu * ldh;
    const HT* hv = h + (long)vv * ldh;
    float* au = agg + (long)uu * lda;
    float* av = agg + (long)vv * lda;
    for (int f = lane; f < P; f += 64) {
        atomicAdd(&av[f], ldv(hu, f));
        atomicAdd(&au[f], ldv(hv, f));
    }
    if (lane == 0) {
        atomicAdd(&av[P], ge);
        atomicAdd(&au[P], ge);
    }
}

__global__ __launch_bounds__(256) void col_stats_kernel(
    const float* __restrict__ X, int Nrows, int F,
    float* __restrict__ sum, float* __restrict__ sumsq)
{
    int tid = threadIdx.x;
    int rowsPerBlock = (Nrows + gridDim.x - 1) / gridDim.x;
    int r0 = blockIdx.x * rowsPerBlock;
    int r1 = min(Nrows, r0 + rowsPerBlock);
    int c0 = tid, c1 = tid + 256;
    float s0 = 0.f, q0 = 0.f, s1 = 0.f, q1 = 0.f;
    for (int r = r0; r < r1; ++r) {
        const float* row = X + (long)r * F;
        if (c0 < F) { float x = row[c0]; s0 += x; q0 += x * x; }
        if (c1 < F) { float x = row[c1]; s1 += x; q1 += x * x; }
    }
    if (c0 < F) { atomicAdd(&sum[c0], s0); atomicAdd(&sumsq[c0], q0); }
    if (c1 < F) { atomicAdd(&sum[c1], s1); atomicAdd(&sumsq[c1], q1); }
}

#define BM 64
#define BNT 64
#define BK 32
template<typename AT0, typename AT1, typename CT>
__global__ __launch_bounds__(256) void gemm_kernel(
    const AT0* __restrict__ A0, int lda0, int cols0,
    const AT1* __restrict__ A1, int lda1,
    const float* __restrict__ Bw,
    CT* __restrict__ C, int ldc,
    int Nrows, int K, int M,
    const float* __restrict__ bn_mean, const float* __restrict__ bn_scale,
    int relu)
{
    __shared__ float sA[BM][BK + 1];
    __shared__ float sB[BNT][BK + 1];
    int row0 = blockIdx.x * BM;
    int col0 = blockIdx.y * BNT;
    int tid = threadIdx.x;
    int tx = tid & 15, ty = tid >> 4;
    float acc[4][4] = {{0.f}};
    for (int k0 = 0; k0 < K; k0 += BK) {
        int i = tid >> 2;
        int j = (tid & 3) * 8;
        int gr = row0 + i;
        int gm = col0 + i;
        #pragma unroll
        for (int s = 0; s < 8; ++s) {
            int gk = k0 + j + s;
            float val = 0.f;
            if (gr < Nrows && gk < K) {
                if (gk < cols0) val = ldv(A0, (long)gr * lda0 + gk);
                else            val = ldv(A1, (long)gr * lda1 + (gk - cols0));
                if (bn_mean) val = (val - bn_mean[gk]) * bn_scale[gk];
            }
            sA[i][j + s] = val;
            float bv = 0.f;
            if (gm < M && gk < K) bv = Bw[(long)gm * K + gk];
            sB[i][j + s] = bv;
        }
        __syncthreads();
        #pragma unroll
        for (int kk = 0; kk < BK; ++kk) {
            float a[4], b[4];
            #pragma unroll
            for (int r = 0; r < 4; ++r) a[r] = sA[ty * 4 + r][kk];
            #pragma unroll
            for (int c = 0; c < 4; ++c) b[c] = sB[tx * 4 + c][kk];
            #pragma unroll
            for (int r = 0; r < 4; ++r)
                #pragma unroll
                for (int c = 0; c < 4; ++c)
                    acc[r][c] += a[r] * b[c];
        }
        __syncthreads();
    }
    #pragma unroll
    for (int r = 0; r < 4; ++r) {
        int gr = row0 + ty * 4 + r;
        if (gr >= Nrows) continue;
        #pragma unroll
        for (int c = 0; c < 4; ++c) {
            int gm = col0 + tx * 4 + c;
            if (gm >= M) continue;
            float vv = acc[r][c];
            if (relu) vv = fmaxf(vv, 0.f);
            stv(C, (long)gr * ldc + gm, vv);
        }
    }
}

// ---------------- legacy link head (fallback path) ----------------
template<typename HT>
__global__ __launch_bounds__(128) void link_kernel(
    const HT* __restrict__ h2, int ldh,
    const int* __restrict__ qu, const int* __restrict__ qv,
    const float* __restrict__ link_h,
    const float* __restrict__ link_o,
    float* __restrict__ out)
{
    __shared__ float sh[1030];
    __shared__ float red[128];
    int q = blockIdx.x;
    int tid = threadIdx.x;
    int a = qu[q], b = qv[q];
    for (int k = tid; k < 515; k += 128) sh[k] = ldv(h2, (long)a * ldh + k);
    for (int k = tid; k < 515; k += 128) sh[515 + k] = ldv(h2, (long)b * ldh + k);
    __syncthreads();
    const float* wrow = link_h + (long)tid * 1030;
    float y = 0.f;
    for (int k = 0; k < 1030; ++k) y += sh[k] * wrow[k];
    y = fmaxf(y, 0.f) * link_o[tid];
    red[tid] = y;
    __syncthreads();
    for (int s = 64; s > 0; s >>= 1) {
        if (tid < s) red[tid] += red[tid + s];
        __syncthreads();
    }
    if (tid == 0) out[q] = red[0];
}

// ---------------- launch ----------------
extern "C" void kernel_launch(void* const* d_in, const int* in_sizes, int n_in,
                              void* d_out, int out_size, void* d_ws, size_t ws_size,
                              hipStream_t stream)
{
    const int*   u      = (const int*)d_in[0];
    const int*   v      = (const int*)d_in[1];
    const float* t      = (const float*)d_in[2];
    const int*   qu     = (const int*)d_in[3];
    const int*   qv     = (const int*)d_in[4];
    const float* h0     = (const float*)d_in[5];
    const float* w1_0   = (const float*)d_in[6];
    const float* w2_0   = (const float*)d_in[7];
    const float* w1_1   = (const float*)d_in[8];
    const float* w2_1   = (const float*)d_in[9];
    const float* link_h = (const float*)d_in[10];
    const float* link_o = (const float*)d_in[11];
    const float* node_h = (const float*)d_in[12];
    const float* node_o = (const float*)d_in[13];

    float* out_link = (float*)d_out;
    float* out_node = (float*)d_out + QQ;

    char* wsb = (char*)d_ws;

    float* stats = (float*)wsb;  // 4096 floats
    float* sum1 = stats,         * sumsq1 = stats + 512;
    float* mean1 = stats + 1024, * scale1 = stats + 1536;
    float* sum2 = stats + 2048,  * sumsq2 = stats + 2560;
    float* mean2 = stats + 3072, * scale2 = stats + 3584;

    if (ws_size >= 217000000ull) {
        // ================= FAST: CSR-gather + full-MFMA path (216.1 MB) =================
        bf16* wf1_0 = (bf16*)(wsb + 16384);        // 256 x 160 (BN-folded, runtime)
        bf16* wb2_0 = (bf16*)(wsb + 98304);        // 384 x 288
        bf16* wf1_1 = (bf16*)(wsb + 319488);       // 384 x 288 (BN-folded, runtime)
        bf16* wb2_1 = (bf16*)(wsb + 540672);       // 640 x 544
        bf16* wbnh  = (bf16*)(wsb + 1236992);      // 128 x 544
        bf16* wbno  = (bf16*)(wsb + 1376256);      // 128 x 128
        float* bias1 = (float*)(wsb + 1409024);    // 256
        float* bias2 = (float*)(wsb + 1410048);    // 512
        float* gsum = (float*)(wsb + 1412096);     // N
        int*   deg  = (int*)  (wsb + 1812096);     // N
        int*   rowp = (int*)  (wsb + 2212096);     // N+1
        int*   cur  = (int*)  (wsb + 2612104);     // N
        int*   bsum = (int*)  (wsb + 3012104);     // 256
        int*   boff = (int*)  (wsb + 3013128);     // 256
        int*   adj  = (int*)  (wsb + 3016200);     // 2E
        bf16*  wlk  = (bf16*) (wsb + 6220000);     // 128 x 1056
        bf16* h1   = (bf16*)(wsb + 6500000ull);    // A: N x 264
        bf16* tmpb = (bf16*)(wsb + 6500000ull);    //    node hidden (aliases A)
        bf16* z0   = (bf16*)(wsb + 59300000ull);   // C: N x 136
        bf16* h0b  = (bf16*)(wsb + 86500000ull);   //    N x 128
        bf16* z1   = (bf16*)(wsb + 59300000ull);   //    N x 264 (C reused)
        bf16* hq   = (bf16*)(wsb + 59300000ull);   //    Q x 1056 (C reused)
        float* tmpl = (float*)(wsb + 70000000ull); //    Q x 128 f32
        bf16* aggb = (bf16*)(wsb + 112100000ull);  // B: N x 136 / N x 264
        bf16* h2   = (bf16*)(wsb + 112100000ull);  // D: N x 520 (aliases B)

        const int gx = (NN + 127) / 128;           // 782
        const int chunk = (NN + NCHUNK - 1) / NCHUNK;

        zero_kernel<<<16, 256, 0, stream>>>(stats, 4096);
        zero_kernel<<<64, 256, 0, stream>>>(gsum, 200000);

        wprep_kernel<<<432, 256, 0, stream>>>(w2_0, 257, 257, 128, 128, 129, 288, 384, wb2_0);
        wprep_kernel<<<1360, 256, 0, stream>>>(w2_1, 515, 515, 257, 272, 258, 544, 640, wb2_1);
        wprep_kernel<<<272, 256, 0, stream>>>(node_h, 515, 128, 515, 544, 0, 544, 128, wbnh);
        wprep_kernel<<<64, 256, 0, stream>>>(node_o, 128, 10, 128, 128, 0, 128, 128, wbno);
        wprep_kernel<<<528, 256, 0, stream>>>(link_h, 1030, 128, 515, 520, 515, 1056, 128, wlk);
        wprep_kernel<<<50000, 256, 0, stream>>>(h0, 128, NN, 128, 128, 0, 128, NN, h0b);

        csr_count_kernel<<<(EE + 255) / 256, 256, 0, stream>>>(u, v, EE, deg);
        csr_chunksum_kernel<<<NCHUNK, 256, 0, stream>>>(deg, NN, chunk, bsum);
        csr_scanb_kernel<<<1, 64, 0, stream>>>(bsum, boff);
        csr_rowp_kernel<<<NCHUNK, 64, 0, stream>>>(deg, boff, NN, chunk, rowp, cur);
        csr_fill_kernel<<<(EE + 255) / 256, 256, 0, stream>>>(u, v, t, EE, cur, adj, gsum);

        // ---- layer 1 ----
        gather_l1_kernel<<<NN / 4, 256, 0, stream>>>(h0b, rowp, adj, gsum, aggb, NN);
        col_stats_b_kernel<<<512, 256, 0, stream>>>(aggb, 136, NN, 129, sum1, sumsq1);
        bn_finalize_kernel<<<2, 256, 0, stream>>>(sum1, sumsq1, 129, (float)NN, mean1, scale1);
        wfold_kernel<<<256, 256, 0, stream>>>(w1_0, 129, 129, mean1, scale1, 160, 256, wf1_0, bias1);
        mfma_gemm_kernel<bf16><<<gx * 2, 256, 0, stream>>>(
            aggb, 136, 160, aggb, 136, wf1_0, 160, bias1, z0, 136, NN, 129, 136, 1, 2);
        mfma_gemm_kernel<bf16><<<gx * 3, 256, 0, stream>>>(
            h0b, 128, 128, z0, 136, wb2_0, 288, nullptr, h1, 264, NN, 257, 264, 0, 3);

        // ---- layer 2 ----
        gather_l2_kernel<<<NN / 4, 256, 0, stream>>>(h1, rowp, adj, gsum, aggb, NN);
        col_stats_b_kernel<<<512, 256, 0, stream>>>(aggb, 264, NN, 258, sum2, sumsq2);
        bn_finalize_kernel<<<2, 256, 0, stream>>>(sum2, sumsq2, 258, (float)NN, mean2, scale2);
        wfold_kernel<<<384, 256, 0, stream>>>(w1_1, 258, 258, mean2, scale2, 288, 384, wf1_1, bias2);
        mfma_gemm_kernel<bf16><<<gx * 3, 256, 0, stream>>>(
            aggb, 264, 288, aggb, 264, wf1_1, 288, bias2, z1, 264, NN, 258, 264, 1, 3);
        mfma_gemm_kernel<bf16><<<gx * 5, 256, 0, stream>>>(
            h1, 264, 272, z1, 264, wb2_1, 544, nullptr, h2, 520, NN, 515, 520, 0, 5);

        // ---- node head (MFMA) ----
        mfma_gemm_kernel<bf16><<<gx, 256, 0, stream>>>(
            h2, 520, 544, h2, 520, wbnh, 544, nullptr, tmpb, 128, NN, 128, 128, 1, 1);
        mfma_gemm_kernel<float><<<gx, 256, 0, stream>>>(
            tmpb, 128, 128, tmpb, 128, wbno, 128, nullptr, out_node, CLASSES, NN, 10, 10, 0, 1);

        // ---- link head ----
        link_gather_kernel<<<QQ / 4, 256, 0, stream>>>(h2, qu, qv, hq);
        mfma_gemm_kernel<float><<<QQ / 128, 256, 0, stream>>>(
            hq, 1056, 1056, hq, 1056, wlk, 1056, nullptr, tmpl, 128, QQ, 128, 128, 1, 1);
        link_dot_kernel<<<QQ / 4, 256, 0, stream>>>(tmpl, link_o, out_link);
    } else {
        // ================= FALLBACK: round-1 tier-B (proven) =================
        const int gx = (NN + BM - 1) / BM;
        const int scatter_blocks = (EE * 64 + 255) / 256;
        float* agg = (float*)(wsb + 16384);
        bf16*  h2b = (bf16*) (wsb + 16384);
        bf16*  h1b = (bf16*) (wsb + 16384 + 103200000ull);
        bf16*  zb  = (bf16*) (wsb + 16384 + 154600000ull);
        float* tmp = (float*)(wsb + 16384 + 154600000ull);

        zero_kernel<<<16, 256, 0, stream>>>(stats, 4096);

        zero_kernel<<<2048, 256, 0, stream>>>(agg, (size_t)NN * 129);
        scatter_edges_kernel<float><<<scatter_blocks, 256, 0, stream>>>(
            h0, 128, 128, u, v, t, EE, agg, 129);
        col_stats_kernel<<<512, 256, 0, stream>>>(agg, NN, 129, sum1, sumsq1);
        bn_finalize_kernel<<<2, 256, 0, stream>>>(sum1, sumsq1, 129, (float)NN, mean1, scale1);
        gemm_kernel<float, float, bf16><<<dim3(gx, 3), 256, 0, stream>>>(
            agg, 129, 129, (const float*)nullptr, 0, w1_0, zb, 129, NN, 129, 129, mean1, scale1, 1);
        gemm_kernel<float, bf16, bf16><<<dim3(gx, 5), 256, 0, stream>>>(
            h0, 128, 128, zb, 129, w2_0, h1b, 257, NN, 257, 257, nullptr, nullptr, 0);

        zero_kernel<<<2048, 256, 0, stream>>>(agg, (size_t)NN * 258);
        scatter_edges_kernel<bf16><<<scatter_blocks, 256, 0, stream>>>(
            h1b, 257, 257, u, v, t, EE, agg, 258);
        col_stats_kernel<<<512, 256, 0, stream>>>(agg, NN, 258, sum2, sumsq2);
        bn_finalize_kernel<<<2, 256, 0, stream>>>(sum2, sumsq2, 258, (float)NN, mean2, scale2);
        gemm_kernel<float, float, bf16><<<dim3(gx, 5), 256, 0, stream>>>(
            agg, 258, 258, (const float*)nullptr, 0, w1_1, zb, 258, NN, 258, 258, mean2, scale2, 1);
        gemm_kernel<bf16, bf16, bf16><<<dim3(gx, 9), 256, 0, stream>>>(
            h1b, 257, 257, zb, 258, w2_1, h2b, 515, NN, 515, 515, nullptr, nullptr, 0);

        gemm_kernel<bf16, float, float><<<dim3(gx, 2), 256, 0, stream>>>(
            h2b, 515, 515, (const float*)nullptr, 0, node_h, tmp, 128, NN, 515, 128, nullptr, nullptr, 1);
        gemm_kernel<float, float, float><<<dim3(gx, 1), 256, 0, stream>>>(
            tmp, 128, 128, tmp, 128, node_o, out_node, CLASSES, NN, 128, CLASSES, nullptr, nullptr, 0);

        link_kernel<bf16><<<QQ, 128, 0, stream>>>(h2b, 515, qu, qv, link_h, link_o, out_link);
    }
}

// Round 9
// 1000.230 us; speedup vs baseline: 1.1063x; 1.0656x over previous
//
#include <hip/hip_runtime.h>
#include <hip/hip_bf16.h>

#define NN      100000
#define EE      400000
#define QQ      4096
#define CLASSES 10
#define BN_EPS  1e-5f
#define NCHUNK  256

typedef __hip_bfloat16 bf16;
typedef __attribute__((ext_vector_type(8))) short short8v;
typedef __attribute__((ext_vector_type(4))) float float4v;

__device__ inline float ldv(const float* p, long i) { return p[i]; }
__device__ inline float ldv(const bf16*  p, long i) { return __bfloat162float(p[i]); }
__device__ inline void  stv(float* p, long i, float v) { p[i] = v; }
__device__ inline void  stv(bf16*  p, long i, float v) { p[i] = __float2bfloat16(v); }

__device__ inline unsigned short f2b(float f) { bf16 b = __float2bfloat16(f); unsigned short s; __builtin_memcpy(&s, &b, 2); return s; }
__device__ inline float b2f(unsigned short s) { bf16 b; __builtin_memcpy(&b, &s, 2); return __bfloat162float(b); }

__device__ __forceinline__ void gload_lds16(const void* g, void* l) {
    __builtin_amdgcn_global_load_lds(
        (const __attribute__((address_space(1))) void*)g,
        (__attribute__((address_space(3))) void*)l,
        16, 0, 0);
}

// ---------------- zeroing ----------------
__global__ void zero_kernel(float* __restrict__ p, size_t n) {
    size_t i  = (size_t)blockIdx.x * blockDim.x + threadIdx.x;
    size_t st = (size_t)gridDim.x * blockDim.x;
    for (; i < n; i += st) p[i] = 0.f;
}

// ---------------- CSR build ----------------
__global__ void csr_count_kernel(const int* __restrict__ u, const int* __restrict__ v, int E, int* __restrict__ deg) {
    int e = blockIdx.x * 256 + threadIdx.x;
    if (e < E) { atomicAdd(&deg[u[e]], 1); atomicAdd(&deg[v[e]], 1); }
}

__global__ __launch_bounds__(256) void csr_chunksum_kernel(const int* __restrict__ deg, int N, int chunk, int* __restrict__ bsum) {
    __shared__ int sh[256];
    int b = blockIdx.x, tid = threadIdx.x;
    int i0 = b * chunk, i1 = min(N, i0 + chunk);
    int s = 0;
    for (int i = i0 + tid; i < i1; i += 256) s += deg[i];
    sh[tid] = s; __syncthreads();
    for (int st = 128; st > 0; st >>= 1) { if (tid < st) sh[tid] += sh[tid + st]; __syncthreads(); }
    if (tid == 0) bsum[b] = sh[0];
}

__global__ void csr_scanb_kernel(const int* __restrict__ bsum, int* __restrict__ boff) {
    if (threadIdx.x == 0 && blockIdx.x == 0) {
        int r = 0;
        for (int i = 0; i < NCHUNK; ++i) { boff[i] = r; r += bsum[i]; }
    }
}

__global__ void csr_rowp_kernel(const int* __restrict__ deg, const int* __restrict__ boff,
                                int N, int chunk, int* __restrict__ rowp, int* __restrict__ cur) {
    int b = blockIdx.x;
    if (threadIdx.x != 0) return;
    int i0 = b * chunk, i1 = min(N, i0 + chunk);
    int r = boff[b];
    for (int i = i0; i < i1; ++i) { rowp[i] = r; cur[i] = r; r += deg[i]; }
    if (b == NCHUNK - 1) rowp[N] = r;
}

__global__ void csr_fill_kernel(const int* __restrict__ u, const int* __restrict__ v,
                                const float* __restrict__ t, int E,
                                int* __restrict__ cur, int* __restrict__ adj, float* __restrict__ gsum) {
    int e = blockIdx.x * 256 + threadIdx.x;
    if (e >= E) return;
    int a = u[e], b = v[e];
    float tlast = t[E - 1], tfirst = t[0];
    float ge = (tlast - t[e]) / (1.0f + tlast - tfirst);
    int p = atomicAdd(&cur[a], 1); adj[p] = b;
    int q = atomicAdd(&cur[b], 1); adj[q] = a;
    atomicAdd(&gsum[a], ge); atomicAdd(&gsum[b], ge);
}

// ---------------- gather L1 (bf16 input, 4-way neighbor unroll for MLP) ----------------
__global__ __launch_bounds__(256) void gather_l1_kernel(
    const bf16* __restrict__ h0b, const int* __restrict__ rowp, const int* __restrict__ adj,
    const float* __restrict__ gsum, bf16* __restrict__ out, int N)
{
    int n = blockIdx.x * 4 + (threadIdx.x >> 6);
    if (n >= N) return;
    int lane = threadIdx.x & 63;
    float a0 = 0.f, a1 = 0.f;
    int j0 = rowp[n], j1 = rowp[n + 1];
    int j = j0;
    for (; j + 4 <= j1; j += 4) {
        int o0 = adj[j], o1 = adj[j + 1], o2 = adj[j + 2], o3 = adj[j + 3];
        ushort2 x0 = ((const ushort2*)(h0b + (long)o0 * 128))[lane];
        ushort2 x1 = ((const ushort2*)(h0b + (long)o1 * 128))[lane];
        ushort2 x2 = ((const ushort2*)(h0b + (long)o2 * 128))[lane];
        ushort2 x3 = ((const ushort2*)(h0b + (long)o3 * 128))[lane];
        a0 += b2f(x0.x) + b2f(x1.x) + b2f(x2.x) + b2f(x3.x);
        a1 += b2f(x0.y) + b2f(x1.y) + b2f(x2.y) + b2f(x3.y);
    }
    for (; j < j1; ++j) {
        int o = adj[j];
        ushort2 x = ((const ushort2*)(h0b + (long)o * 128))[lane];
        a0 += b2f(x.x); a1 += b2f(x.y);
    }
    bf16* orow = out + (long)n * 136;
    ushort2 pv; pv.x = f2b(a0); pv.y = f2b(a1);
    ((ushort2*)orow)[lane] = pv;
    if (lane == 0) {
        orow[128] = __float2bfloat16(gsum[n]);
        orow[129] = __float2bfloat16(0.f);
    } else if (lane < 4) {
        ushort2 z; z.x = 0; z.y = 0;
        ((ushort2*)(orow + 130))[lane - 1] = z;   // cols 130..135
    }
}

// ---------------- gather L2 (ushort4/lane + 4-way neighbor unroll) ----------------
// lane covers cols 4l..4l+3 (256 cols); col 256 (cS) via lane0 scalar.
__global__ __launch_bounds__(256) void gather_l2_kernel(
    const bf16* __restrict__ h1, const int* __restrict__ rowp, const int* __restrict__ adj,
    const float* __restrict__ gsum, bf16* __restrict__ out, int N)
{
    int n = blockIdx.x * 4 + (threadIdx.x >> 6);
    if (n >= N) return;
    int lane = threadIdx.x & 63;
    float a0 = 0.f, a1 = 0.f, a2 = 0.f, a3 = 0.f, cS = 0.f;
    int j0 = rowp[n], j1 = rowp[n + 1];
    int j = j0;
    for (; j + 4 <= j1; j += 4) {
        int o0 = adj[j], o1 = adj[j + 1], o2 = adj[j + 2], o3 = adj[j + 3];
        ushort4 x0 = ((const ushort4*)(h1 + (long)o0 * 264))[lane];
        ushort4 x1 = ((const ushort4*)(h1 + (long)o1 * 264))[lane];
        ushort4 x2 = ((const ushort4*)(h1 + (long)o2 * 264))[lane];
        ushort4 x3 = ((const ushort4*)(h1 + (long)o3 * 264))[lane];
        a0 += b2f(x0.x) + b2f(x1.x) + b2f(x2.x) + b2f(x3.x);
        a1 += b2f(x0.y) + b2f(x1.y) + b2f(x2.y) + b2f(x3.y);
        a2 += b2f(x0.z) + b2f(x1.z) + b2f(x2.z) + b2f(x3.z);
        a3 += b2f(x0.w) + b2f(x1.w) + b2f(x2.w) + b2f(x3.w);
        if (lane == 0)
            cS += __bfloat162float(h1[(long)o0 * 264 + 256]) + __bfloat162float(h1[(long)o1 * 264 + 256])
                + __bfloat162float(h1[(long)o2 * 264 + 256]) + __bfloat162float(h1[(long)o3 * 264 + 256]);
    }
    for (; j < j1; ++j) {
        int o = adj[j];
        ushort4 x = ((const ushort4*)(h1 + (long)o * 264))[lane];
        a0 += b2f(x.x); a1 += b2f(x.y); a2 += b2f(x.z); a3 += b2f(x.w);
        if (lane == 0) cS += __bfloat162float(h1[(long)o * 264 + 256]);
    }
    bf16* orow = out + (long)n * 264;
    ushort4 pv; pv.x = f2b(a0); pv.y = f2b(a1); pv.z = f2b(a2); pv.w = f2b(a3);
    ((ushort4*)orow)[lane] = pv;
    if (lane == 0) {
        orow[256] = __float2bfloat16(cS);
        orow[257] = __float2bfloat16(gsum[n]);
    } else if (lane < 4) {
        ushort2 z; z.x = 0; z.y = 0;
        ((ushort2*)orow)[128 + lane] = z;   // cols 258..263
    }
}

// ---------------- column stats over bf16 matrix ----------------
__global__ __launch_bounds__(256) void col_stats_b_kernel(
    const bf16* __restrict__ X, int ld, int Nrows, int F,
    float* __restrict__ sum, float* __restrict__ sumsq)
{
    int tid = threadIdx.x;
    int rpb = (Nrows + gridDim.x - 1) / gridDim.x;
    int r0 = blockIdx.x * rpb, r1 = min(Nrows, r0 + rpb);
    int c0 = tid, c1 = tid + 256;
    float s0 = 0.f, q0 = 0.f, s1 = 0.f, q1 = 0.f;
    for (int r = r0; r < r1; ++r) {
        const bf16* row = X + (long)r * ld;
        if (c0 < F) { float x = __bfloat162float(row[c0]); s0 += x; q0 += x * x; }
        if (c1 < F) { float x = __bfloat162float(row[c1]); s1 += x; q1 += x * x; }
    }
    if (c0 < F) { atomicAdd(&sum[c0], s0); atomicAdd(&sumsq[c0], q0); }
    if (c1 < F) { atomicAdd(&sum[c1], s1); atomicAdd(&sumsq[c1], q1); }
}

__global__ void bn_finalize_kernel(const float* __restrict__ sum, const float* __restrict__ sumsq,
                                   int F, float Nf, float* __restrict__ mean, float* __restrict__ scale)
{
    int c = blockIdx.x * blockDim.x + threadIdx.x;
    if (c < F) {
        float m = sum[c] / Nf;
        float var = sumsq[c] / Nf - m * m;
        mean[c] = m;
        scale[c] = 1.0f / sqrtf(var + BN_EPS);
    }
}

// ---------------- fold BN into w1 ----------------
__global__ __launch_bounds__(256) void wfold_kernel(
    const float* __restrict__ w, int Ktot, int M,
    const float* __restrict__ mean, const float* __restrict__ scale,
    int Kpad, int Mpad, bf16* __restrict__ wout, float* __restrict__ bias)
{
    __shared__ float sh[256];
    int m = blockIdx.x;
    int tid = threadIdx.x;
    float bs = 0.f;
    bf16* orow = wout + (long)m * Kpad;
    for (int k = tid; k < Kpad; k += 256) {
        float val = 0.f;
        if (m < M && k < Ktot) {
            float wv = w[(long)m * Ktot + k];
            val = wv * scale[k];
            bs -= mean[k] * scale[k] * wv;
        }
        orow[k] = __float2bfloat16(val);
    }
    sh[tid] = bs; __syncthreads();
    for (int st = 128; st > 0; st >>= 1) { if (tid < st) sh[tid] += sh[tid + st]; __syncthreads(); }
    if (tid == 0 && m < M) bias[m] = sh[0];
}

// ---------------- weight prep ----------------
__global__ void wprep_kernel(const float* __restrict__ w, int Ktot, int M,
                             int K1, int W1, int K2, int Kpad, int Mpad,
                             bf16* __restrict__ out)
{
    int idx = blockIdx.x * 256 + threadIdx.x;
    if (idx >= Mpad * Kpad) return;
    int m = idx / Kpad, k = idx - m * Kpad;
    float val = 0.f;
    if (m < M) {
        if (k < W1) { if (k < K1) val = w[(long)m * Ktot + k]; }
        else { int j = k - W1; if (j < K2) val = w[(long)m * Ktot + K1 + j]; }
    }
    out[idx] = __float2bfloat16(val);
}

// ---------------- MFMA GEMM (XCD-aware bijective swizzle; col-fastest works) ----------------
template<typename CT>
__global__ __launch_bounds__(256) void mfma_gemm_kernel(
    const bf16* __restrict__ A0, int lda0, int W1,
    const bf16* __restrict__ A1, int lda1,
    const bf16* __restrict__ Wb, int Kpad,
    const float* __restrict__ bias,
    CT* __restrict__ C, long ldc, int Nrows, int M, int padlim, int relu, int gy)
{
    __shared__ bf16 sA[128 * 32];
    __shared__ bf16 sB[128 * 32];

    int tid  = threadIdx.x;
    int bid  = blockIdx.x;
    int nwg  = gridDim.x;
    int q    = nwg >> 3, rem = nwg & 7;
    int xcd  = bid & 7;
    int base = (xcd < rem) ? xcd * (q + 1) : rem * (q + 1) + (xcd - rem) * q;
    int wgid = base + (bid >> 3);
    int row0 = (wgid / gy) * 128;
    int col0 = (wgid % gy) * 128;

    int wave = tid >> 6, lane = tid & 63;
    int wr = (wave >> 1) * 64, wc = (wave & 1) * 64;
    int la = lane & 15, hk = lane >> 4;

    float4v acc[4][4];
    #pragma unroll
    for (int i = 0; i < 4; ++i)
        #pragma unroll
        for (int j = 0; j < 4; ++j)
            acc[i][j] = (float4v){0.f, 0.f, 0.f, 0.f};

    const short8v* sA8 = (const short8v*)sA;
    const short8v* sB8 = (const short8v*)sB;

    long offA0[2], offA1[2], offW[2];
    int  kq8_[2];
    char *ldsA_[2], *ldsB_[2];
    #pragma unroll
    for (int h = 0; h < 2; ++h) {
        int c = tid + h * 256;
        int r = c >> 2;
        int kq8 = (c & 3) * 8;
        kq8_[h] = kq8;
        int ga_row = row0 + r; if (ga_row >= Nrows) ga_row = Nrows - 1;
        offA0[h] = (long)ga_row * lda0 + kq8;
        offA1[h] = (long)ga_row * lda1 + kq8 - W1;
        offW[h]  = (long)(col0 + r) * Kpad + kq8;
        ldsA_[h] = (char*)sA + (size_t)c * 16;
        ldsB_[h] = (char*)sB + (size_t)c * 16;
    }

    for (int k0 = 0; k0 < Kpad; k0 += 32) {
        #pragma unroll
        for (int h = 0; h < 2; ++h) {
            int ka = k0 + kq8_[h];
            const bf16* gp = (ka < W1) ? (A0 + offA0[h] + k0) : (A1 + offA1[h] + k0);
            gload_lds16(gp, ldsA_[h]);
            gload_lds16(Wb + offW[h] + k0, ldsB_[h]);
        }
        __syncthreads();

        short8v afr[4], bfr[4];
        #pragma unroll
        for (int mf = 0; mf < 4; ++mf)
            afr[mf] = sA8[(size_t)(wr + mf * 16 + la) * 4 + hk];
        #pragma unroll
        for (int nf = 0; nf < 4; ++nf)
            bfr[nf] = sB8[(size_t)(wc + nf * 16 + la) * 4 + hk];
        #pragma unroll
        for (int mf = 0; mf < 4; ++mf)
            #pragma unroll
            for (int nf = 0; nf < 4; ++nf)
                acc[mf][nf] = __builtin_amdgcn_mfma_f32_16x16x32_bf16(
                    afr[mf], bfr[nf], acc[mf][nf], 0, 0, 0);
        __syncthreads();
    }

    #pragma unroll
    for (int mf = 0; mf < 4; ++mf) {
        #pragma unroll
        for (int r = 0; r < 4; ++r) {
            long grow = row0 + wr + mf * 16 + hk * 4 + r;
            if (grow >= Nrows) continue;
            #pragma unroll
            for (int nf = 0; nf < 4; ++nf) {
                int gcol = col0 + wc + nf * 16 + la;
                if (gcol >= padlim) continue;
                float vv = 0.f;
                if (gcol < M) {
                    vv = acc[mf][nf][r];
                    if (bias) vv += bias[gcol];
                    if (relu) vv = fmaxf(vv, 0.f);
                }
                stv(C, grow * ldc + gcol, vv);
            }
        }
    }
}

// ---------------- link head: gather hq rows, then MFMA, then dot ----------------
__global__ __launch_bounds__(256) void link_gather_kernel(
    const bf16* __restrict__ h2, const int* __restrict__ qu, const int* __restrict__ qv,
    bf16* __restrict__ hq)
{
    int q = blockIdx.x * 4 + (threadIdx.x >> 6);
    if (q >= QQ) return;
    int lane = threadIdx.x & 63;
    const ushort4* ra4 = (const ushort4*)(h2 + (long)qu[q] * 520);
    const ushort4* rb4 = (const ushort4*)(h2 + (long)qv[q] * 520);
    ushort4* o4 = (ushort4*)(hq + (long)q * 1056);
    #pragma unroll 3
    for (int k = lane; k < 130; k += 64) o4[k] = ra4[k];
    #pragma unroll 3
    for (int k = lane; k < 130; k += 64) o4[130 + k] = rb4[k];
    if (lane < 4) { ushort4 z; z.x = z.y = z.z = z.w = 0; o4[260 + lane] = z; }
}

__global__ __launch_bounds__(256) void link_dot_kernel(
    const float* __restrict__ tmpl, const float* __restrict__ link_o, float* __restrict__ out)
{
    int q = blockIdx.x * 4 + (threadIdx.x >> 6);
    if (q >= QQ) return;
    int lane = threadIdx.x & 63;
    const float* r = tmpl + (long)q * 128;
    float s = r[lane] * link_o[lane] + r[lane + 64] * link_o[lane + 64];
    #pragma unroll
    for (int off = 32; off > 0; off >>= 1) s += __shfl_xor(s, off, 64);
    if (lane == 0) out[q] = s;
}

// ---------------- fallback-path kernels (round-1 tier-B, proven) ----------------
template<typename HT>
__global__ __launch_bounds__(256) void scatter_edges_kernel(
    const HT* __restrict__ h, int ldh, int P,
    const int* __restrict__ u, const int* __restrict__ v,
    const float* __restrict__ t, int E,
    float* __restrict__ agg, int lda)
{
    long gid = (long)blockIdx.x * blockDim.x + threadIdx.x;
    int e = (int)(gid >> 6);
    int lane = (int)(gid & 63);
    if (e >= E) return;
    int uu = u[e], vv = v[e];
    float tlast = t[E - 1], tfirst = t[0];
    float ge = (tlast - t[e]) / (1.0f + tlast - tfirst);
    const HT* hu = h + (long)uu * ldh;
    const HT* hv = h + (long)vv * ldh;
    float* au = agg + (long)uu * lda;
    float* av = agg + (long)vv * lda;
    for (int f = lane; f < P; f += 64) {
        atomicAdd(&av[f], ldv(hu, f));
        atomicAdd(&au[f], ldv(hv, f));
    }
    if (lane == 0) {
        atomicAdd(&av[P], ge);
        atomicAdd(&au[P], ge);
    }
}

__global__ __launch_bounds__(256) void col_stats_kernel(
    const float* __restrict__ X, int Nrows, int F,
    float* __restrict__ sum, float* __restrict__ sumsq)
{
    int tid = threadIdx.x;
    int rowsPerBlock = (Nrows + gridDim.x - 1) / gridDim.x;
    int r0 = blockIdx.x * rowsPerBlock;
    int r1 = min(Nrows, r0 + rowsPerBlock);
    int c0 = tid, c1 = tid + 256;
    float s0 = 0.f, q0 = 0.f, s1 = 0.f, q1 = 0.f;
    for (int r = r0; r < r1; ++r) {
        const float* row = X + (long)r * F;
        if (c0 < F) { float x = row[c0]; s0 += x; q0 += x * x; }
        if (c1 < F) { float x = row[c1]; s1 += x; q1 += x * x; }
    }
    if (c0 < F) { atomicAdd(&sum[c0], s0); atomicAdd(&sumsq[c0], q0); }
    if (c1 < F) { atomicAdd(&sum[c1], s1); atomicAdd(&sumsq[c1], q1); }
}

#define BM 64
#define BNT 64
#define BK 32
template<typename AT0, typename AT1, typename CT>
__global__ __launch_bounds__(256) void gemm_kernel(
    const AT0* __restrict__ A0, int lda0, int cols0,
    const AT1* __restrict__ A1, int lda1,
    const float* __restrict__ Bw,
    CT* __restrict__ C, int ldc,
    int Nrows, int K, int M,
    const float* __restrict__ bn_mean, const float* __restrict__ bn_scale,
    int relu)
{
    __shared__ float sA[BM][BK + 1];
    __shared__ float sB[BNT][BK + 1];
    int row0 = blockIdx.x * BM;
    int col0 = blockIdx.y * BNT;
    int tid = threadIdx.x;
    int tx = tid & 15, ty = tid >> 4;
    float acc[4][4] = {{0.f}};
    for (int k0 = 0; k0 < K; k0 += BK) {
        int i = tid >> 2;
        int j = (tid & 3) * 8;
        int gr = row0 + i;
        int gm = col0 + i;
        #pragma unroll
        for (int s = 0; s < 8; ++s) {
            int gk = k0 + j + s;
            float val = 0.f;
            if (gr < Nrows && gk < K) {
                if (gk < cols0) val = ldv(A0, (long)gr * lda0 + gk);
                else            val = ldv(A1, (long)gr * lda1 + (gk - cols0));
                if (bn_mean) val = (val - bn_mean[gk]) * bn_scale[gk];
            }
            sA[i][j + s] = val;
            float bv = 0.f;
            if (gm < M && gk < K) bv = Bw[(long)gm * K + gk];
            sB[i][j + s] = bv;
        }
        __syncthreads();
        #pragma unroll
        for (int kk = 0; kk < BK; ++kk) {
            float a[4], b[4];
            #pragma unroll
            for (int r = 0; r < 4; ++r) a[r] = sA[ty * 4 + r][kk];
            #pragma unroll
            for (int c = 0; c < 4; ++c) b[c] = sB[tx * 4 + c][kk];
            #pragma unroll
            for (int r = 0; r < 4; ++r)
                #pragma unroll
                for (int c = 0; c < 4; ++c)
                    acc[r][c] += a[r] * b[c];
        }
        __syncthreads();
    }
    #pragma unroll
    for (int r = 0; r < 4; ++r) {
        int gr = row0 + ty * 4 + r;
        if (gr >= Nrows) continue;
        #pragma unroll
        for (int c = 0; c < 4; ++c) {
            int gm = col0 + tx * 4 + c;
            if (gm >= M) continue;
            float vv = acc[r][c];
            if (relu) vv = fmaxf(vv, 0.f);
            stv(C, (long)gr * ldc + gm, vv);
        }
    }
}

// ---------------- legacy link head (fallback path) ----------------
template<typename HT>
__global__ __launch_bounds__(128) void link_kernel(
    const HT* __restrict__ h2, int ldh,
    const int* __restrict__ qu, const int* __restrict__ qv,
    const float* __restrict__ link_h,
    const float* __restrict__ link_o,
    float* __restrict__ out)
{
    __shared__ float sh[1030];
    __shared__ float red[128];
    int q = blockIdx.x;
    int tid = threadIdx.x;
    int a = qu[q], b = qv[q];
    for (int k = tid; k < 515; k += 128) sh[k] = ldv(h2, (long)a * ldh + k);
    for (int k = tid; k < 515; k += 128) sh[515 + k] = ldv(h2, (long)b * ldh + k);
    __syncthreads();
    const float* wrow = link_h + (long)tid * 1030;
    float y = 0.f;
    for (int k = 0; k < 1030; ++k) y += sh[k] * wrow[k];
    y = fmaxf(y, 0.f) * link_o[tid];
    red[tid] = y;
    __syncthreads();
    for (int s = 64; s > 0; s >>= 1) {
        if (tid < s) red[tid] += red[tid + s];
        __syncthreads();
    }
    if (tid == 0) out[q] = red[0];
}

// ---------------- launch ----------------
extern "C" void kernel_launch(void* const* d_in, const int* in_sizes, int n_in,
                              void* d_out, int out_size, void* d_ws, size_t ws_size,
                              hipStream_t stream)
{
    const int*   u      = (const int*)d_in[0];
    const int*   v      = (const int*)d_in[1];
    const float* t      = (const float*)d_in[2];
    const int*   qu     = (const int*)d_in[3];
    const int*   qv     = (const int*)d_in[4];
    const float* h0     = (const float*)d_in[5];
    const float* w1_0   = (const float*)d_in[6];
    const float* w2_0   = (const float*)d_in[7];
    const float* w1_1   = (const float*)d_in[8];
    const float* w2_1   = (const float*)d_in[9];
    const float* link_h = (const float*)d_in[10];
    const float* link_o = (const float*)d_in[11];
    const float* node_h = (const float*)d_in[12];
    const float* node_o = (const float*)d_in[13];

    float* out_link = (float*)d_out;
    float* out_node = (float*)d_out + QQ;

    char* wsb = (char*)d_ws;

    float* stats = (float*)wsb;  // 4096 floats
    float* sum1 = stats,         * sumsq1 = stats + 512;
    float* mean1 = stats + 1024, * scale1 = stats + 1536;
    float* sum2 = stats + 2048,  * sumsq2 = stats + 2560;
    float* mean2 = stats + 3072, * scale2 = stats + 3584;

    if (ws_size >= 217000000ull) {
        // ================= FAST: CSR-gather + full-MFMA path (216.1 MB) =================
        bf16* wf1_0 = (bf16*)(wsb + 16384);        // 256 x 160 (BN-folded, runtime)
        bf16* wb2_0 = (bf16*)(wsb + 98304);        // 384 x 288
        bf16* wf1_1 = (bf16*)(wsb + 319488);       // 384 x 288 (BN-folded, runtime)
        bf16* wb2_1 = (bf16*)(wsb + 540672);       // 640 x 544
        bf16* wbnh  = (bf16*)(wsb + 1236992);      // 128 x 544
        bf16* wbno  = (bf16*)(wsb + 1376256);      // 128 x 128
        float* bias1 = (float*)(wsb + 1409024);    // 256
        float* bias2 = (float*)(wsb + 1410048);    // 512
        float* gsum = (float*)(wsb + 1412096);     // N
        int*   deg  = (int*)  (wsb + 1812096);     // N
        int*   rowp = (int*)  (wsb + 2212096);     // N+1
        int*   cur  = (int*)  (wsb + 2612104);     // N
        int*   bsum = (int*)  (wsb + 3012104);     // 256
        int*   boff = (int*)  (wsb + 3013128);     // 256
        int*   adj  = (int*)  (wsb + 3016200);     // 2E
        bf16*  wlk  = (bf16*) (wsb + 6220000);     // 128 x 1056
        bf16* h1   = (bf16*)(wsb + 6500000ull);    // A: N x 264
        bf16* tmpb = (bf16*)(wsb + 6500000ull);    //    node hidden (aliases A)
        bf16* z0   = (bf16*)(wsb + 59300000ull);   // C: N x 136
        bf16* h0b  = (bf16*)(wsb + 86500000ull);   //    N x 128
        bf16* z1   = (bf16*)(wsb + 59300000ull);   //    N x 264 (C reused)
        bf16* hq   = (bf16*)(wsb + 59300000ull);   //    Q x 1056 (C reused)
        float* tmpl = (float*)(wsb + 70000000ull); //    Q x 128 f32
        bf16* aggb = (bf16*)(wsb + 112100000ull);  // B: N x 136 / N x 264
        bf16* h2   = (bf16*)(wsb + 112100000ull);  // D: N x 520 (aliases B)

        const int gx = (NN + 127) / 128;           // 782
        const int chunk = (NN + NCHUNK - 1) / NCHUNK;

        zero_kernel<<<16, 256, 0, stream>>>(stats, 4096);
        zero_kernel<<<64, 256, 0, stream>>>(gsum, 200000);

        wprep_kernel<<<432, 256, 0, stream>>>(w2_0, 257, 257, 128, 128, 129, 288, 384, wb2_0);
        wprep_kernel<<<1360, 256, 0, stream>>>(w2_1, 515, 515, 257, 272, 258, 544, 640, wb2_1);
        wprep_kernel<<<272, 256, 0, stream>>>(node_h, 515, 128, 515, 544, 0, 544, 128, wbnh);
        wprep_kernel<<<64, 256, 0, stream>>>(node_o, 128, 10, 128, 128, 0, 128, 128, wbno);
        wprep_kernel<<<528, 256, 0, stream>>>(link_h, 1030, 128, 515, 520, 515, 1056, 128, wlk);
        wprep_kernel<<<50000, 256, 0, stream>>>(h0, 128, NN, 128, 128, 0, 128, NN, h0b);

        csr_count_kernel<<<(EE + 255) / 256, 256, 0, stream>>>(u, v, EE, deg);
        csr_chunksum_kernel<<<NCHUNK, 256, 0, stream>>>(deg, NN, chunk, bsum);
        csr_scanb_kernel<<<1, 64, 0, stream>>>(bsum, boff);
        csr_rowp_kernel<<<NCHUNK, 64, 0, stream>>>(deg, boff, NN, chunk, rowp, cur);
        csr_fill_kernel<<<(EE + 255) / 256, 256, 0, stream>>>(u, v, t, EE, cur, adj, gsum);

        // ---- layer 1 ----
        gather_l1_kernel<<<NN / 4, 256, 0, stream>>>(h0b, rowp, adj, gsum, aggb, NN);
        col_stats_b_kernel<<<512, 256, 0, stream>>>(aggb, 136, NN, 129, sum1, sumsq1);
        bn_finalize_kernel<<<2, 256, 0, stream>>>(sum1, sumsq1, 129, (float)NN, mean1, scale1);
        wfold_kernel<<<256, 256, 0, stream>>>(w1_0, 129, 129, mean1, scale1, 160, 256, wf1_0, bias1);
        mfma_gemm_kernel<bf16><<<gx * 2, 256, 0, stream>>>(
            aggb, 136, 160, aggb, 136, wf1_0, 160, bias1, z0, 136, NN, 129, 136, 1, 2);
        mfma_gemm_kernel<bf16><<<gx * 3, 256, 0, stream>>>(
            h0b, 128, 128, z0, 136, wb2_0, 288, nullptr, h1, 264, NN, 257, 264, 0, 3);

        // ---- layer 2 ----
        gather_l2_kernel<<<NN / 4, 256, 0, stream>>>(h1, rowp, adj, gsum, aggb, NN);
        col_stats_b_kernel<<<512, 256, 0, stream>>>(aggb, 264, NN, 258, sum2, sumsq2);
        bn_finalize_kernel<<<2, 256, 0, stream>>>(sum2, sumsq2, 258, (float)NN, mean2, scale2);
        wfold_kernel<<<384, 256, 0, stream>>>(w1_1, 258, 258, mean2, scale2, 288, 384, wf1_1, bias2);
        mfma_gemm_kernel<bf16><<<gx * 3, 256, 0, stream>>>(
            aggb, 264, 288, aggb, 264, wf1_1, 288, bias2, z1, 264, NN, 258, 264, 1, 3);
        mfma_gemm_kernel<bf16><<<gx * 5, 256, 0, stream>>>(
            h1, 264, 272, z1, 264, wb2_1, 544, nullptr, h2, 520, NN, 515, 520, 0, 5);

        // ---- node head (MFMA) ----
        mfma_gemm_kernel<bf16><<<gx, 256, 0, stream>>>(
            h2, 520, 544, h2, 520, wbnh, 544, nullptr, tmpb, 128, NN, 128, 128, 1, 1);
        mfma_gemm_kernel<float><<<gx, 256, 0, stream>>>(
            tmpb, 128, 128, tmpb, 128, wbno, 128, nullptr, out_node, CLASSES, NN, 10, 10, 0, 1);

        // ---- link head ----
        link_gather_kernel<<<QQ / 4, 256, 0, stream>>>(h2, qu, qv, hq);
        mfma_gemm_kernel<float><<<QQ / 128, 256, 0, stream>>>(
            hq, 1056, 1056, hq, 1056, wlk, 1056, nullptr, tmpl, 128, QQ, 128, 128, 1, 1);
        link_dot_kernel<<<QQ / 4, 256, 0, stream>>>(tmpl, link_o, out_link);
    } else {
        // ================= FALLBACK: round-1 tier-B (proven) =================
        const int gx = (NN + BM - 1) / BM;
        const int scatter_blocks = (EE * 64 + 255) / 256;
        float* agg = (float*)(wsb + 16384);
        bf16*  h2b = (bf16*) (wsb + 16384);
        bf16*  h1b = (bf16*) (wsb + 16384 + 103200000ull);
        bf16*  zb  = (bf16*) (wsb + 16384 + 154600000ull);
        float* tmp = (float*)(wsb + 16384 + 154600000ull);

        zero_kernel<<<16, 256, 0, stream>>>(stats, 4096);

        zero_kernel<<<2048, 256, 0, stream>>>(agg, (size_t)NN * 129);
        scatter_edges_kernel<float><<<scatter_blocks, 256, 0, stream>>>(
            h0, 128, 128, u, v, t, EE, agg, 129);
        col_stats_kernel<<<512, 256, 0, stream>>>(agg, NN, 129, sum1, sumsq1);
        bn_finalize_kernel<<<2, 256, 0, stream>>>(sum1, sumsq1, 129, (float)NN, mean1, scale1);
        gemm_kernel<float, float, bf16><<<dim3(gx, 3), 256, 0, stream>>>(
            agg, 129, 129, (const float*)nullptr, 0, w1_0, zb, 129, NN, 129, 129, mean1, scale1, 1);
        gemm_kernel<float, bf16, bf16><<<dim3(gx, 5), 256, 0, stream>>>(
            h0, 128, 128, zb, 129, w2_0, h1b, 257, NN, 257, 257, nullptr, nullptr, 0);

        zero_kernel<<<2048, 256, 0, stream>>>(agg, (size_t)NN * 258);
        scatter_edges_kernel<bf16><<<scatter_blocks, 256, 0, stream>>>(
            h1b, 257, 257, u, v, t, EE, agg, 258);
        col_stats_kernel<<<512, 256, 0, stream>>>(agg, NN, 258, sum2, sumsq2);
        bn_finalize_kernel<<<2, 256, 0, stream>>>(sum2, sumsq2, 258, (float)NN, mean2, scale2);
        gemm_kernel<float, float, bf16><<<dim3(gx, 5), 256, 0, stream>>>(
            agg, 258, 258, (const float*)nullptr, 0, w1_1, zb, 258, NN, 258, 258, mean2, scale2, 1);
        gemm_kernel<bf16, bf16, bf16><<<dim3(gx, 9), 256, 0, stream>>>(
            h1b, 257, 257, zb, 258, w2_1, h2b, 515, NN, 515, 515, nullptr, nullptr, 0);

        gemm_kernel<bf16, float, float><<<dim3(gx, 2), 256, 0, stream>>>(
            h2b, 515, 515, (const float*)nullptr, 0, node_h, tmp, 128, NN, 515, 128, nullptr, nullptr, 1);
        gemm_kernel<float, float, float><<<dim3(gx, 1), 256, 0, stream>>>(
            tmp, 128, 128, tmp, 128, node_o, out_node, CLASSES, NN, 128, CLASSES, nullptr, nullptr, 0);

        link_kernel<bf16><<<QQ, 128, 0, stream>>>(h2b, 515, qu, qv, link_h, link_o, out_link);
    }
}